// Round 1
// baseline (24569.276 us; speedup 1.0000x reference)
//
#include <hip/hip_runtime.h>
#include <hip/hip_bf16.h>
#include <math.h>

#define Tn   2048
#define Cn   1536
#define Vn   32000
#define NHn  12
#define NKVn 4
#define Dn   128
#define HIDn 2048
#define En   8
#define Kn   2
#define Ln   2
#define NREPn 3
#define EPSn 1e-6f

// ---------------- embed: x = emb[tok] + pos ----------------
__global__ void embed_k(const int* __restrict__ tok, const float* __restrict__ emb,
                        const float* __restrict__ pos, float* __restrict__ x) {
  int n = blockIdx.x;
  int t = threadIdx.x;
  int id = tok[n];
  const float* er = emb + (size_t)id * Cn;
  const float* pr = pos + (size_t)n * Cn;
  float* xr = x + (size_t)n * Cn;
  for (int c = t; c < Cn; c += 256) xr[c] = er[c] + pr[c];
}

// ---------------- RMSNorm ----------------
__global__ void rmsnorm_k(const float* __restrict__ x, const float* __restrict__ w,
                          float* __restrict__ out) {
  int n = blockIdx.x, t = threadIdx.x;
  const float* xr = x + (size_t)n * Cn;
  float v[6];
  float ss = 0.f;
#pragma unroll
  for (int i = 0; i < 6; i++) { v[i] = xr[t + i * 256]; ss += v[i] * v[i]; }
  for (int off = 32; off > 0; off >>= 1) ss += __shfl_down(ss, off, 64);
  __shared__ float red[4];
  __shared__ float rtot;
  int wave = t >> 6, lane = t & 63;
  if (lane == 0) red[wave] = ss;
  __syncthreads();
  if (t == 0) rtot = rsqrtf((red[0] + red[1] + red[2] + red[3]) / (float)Cn + EPSn);
  __syncthreads();
  float r = rtot;
  float* orow = out + (size_t)n * Cn;
#pragma unroll
  for (int i = 0; i < 6; i++) { int c = t + i * 256; orow[c] = v[i] * r * w[c]; }
}

// ---------------- generic fp32 GEMM: C = A[M,K] @ B[K,N] (+res) ----------------
__global__ void gemm_nn_k(const float* __restrict__ A, const float* __restrict__ B,
                          const float* __restrict__ res, float* __restrict__ Co,
                          int M, int N, int K) {
  __shared__ float As[16][65];
  __shared__ float Bs[16][65];
  int t = threadIdx.x;
  int bm = blockIdx.x * 64, bn = blockIdx.y * 64;
  int tm = t >> 4, tn = t & 15;
  int lr = t >> 4, lk = t & 15;    // A load coords
  int lbk = t >> 6, lbn = t & 63;  // B load coords
  float acc[16];
#pragma unroll
  for (int i = 0; i < 16; i++) acc[i] = 0.f;
  for (int k0 = 0; k0 < K; k0 += 16) {
#pragma unroll
    for (int i = 0; i < 4; i++)
      As[lk][lr + 16 * i] = A[(size_t)(bm + lr + 16 * i) * K + k0 + lk];
#pragma unroll
    for (int i = 0; i < 4; i++)
      Bs[lbk + 4 * i][lbn] = B[(size_t)(k0 + lbk + 4 * i) * N + bn + lbn];
    __syncthreads();
#pragma unroll
    for (int kk = 0; kk < 16; kk++) {
      float a[4], b[4];
#pragma unroll
      for (int i = 0; i < 4; i++) a[i] = As[kk][tm * 4 + i];
#pragma unroll
      for (int j = 0; j < 4; j++) b[j] = Bs[kk][tn * 4 + j];
#pragma unroll
      for (int i = 0; i < 4; i++)
#pragma unroll
        for (int j = 0; j < 4; j++) acc[i * 4 + j] += a[i] * b[j];
    }
    __syncthreads();
  }
#pragma unroll
  for (int i = 0; i < 4; i++) {
    size_t row = (size_t)(bm + tm * 4 + i);
#pragma unroll
    for (int j = 0; j < 4; j++) {
      size_t idx = row * N + bn + tn * 4 + j;
      float vv = acc[i * 4 + j];
      if (res) vv += res[idx];
      Co[idx] = vv;
    }
  }
}

// ---------------- GEMM with B transposed: C = A[M,K] @ Bt[N,K]^T ----------------
__global__ void gemm_nt_k(const float* __restrict__ A, const float* __restrict__ Bt,
                          float* __restrict__ Co, int M, int N, int K) {
  __shared__ float As[16][65];
  __shared__ float Bs[16][65];
  int t = threadIdx.x;
  int bm = blockIdx.x * 64, bn = blockIdx.y * 64;
  int tm = t >> 4, tn = t & 15;
  int lr = t >> 4, lk = t & 15;
  float acc[16];
#pragma unroll
  for (int i = 0; i < 16; i++) acc[i] = 0.f;
  for (int k0 = 0; k0 < K; k0 += 16) {
#pragma unroll
    for (int i = 0; i < 4; i++)
      As[lk][lr + 16 * i] = A[(size_t)(bm + lr + 16 * i) * K + k0 + lk];
#pragma unroll
    for (int i = 0; i < 4; i++)
      Bs[lk][lr + 16 * i] = Bt[(size_t)(bn + lr + 16 * i) * K + k0 + lk];
    __syncthreads();
#pragma unroll
    for (int kk = 0; kk < 16; kk++) {
      float a[4], b[4];
#pragma unroll
      for (int i = 0; i < 4; i++) a[i] = As[kk][tm * 4 + i];
#pragma unroll
      for (int j = 0; j < 4; j++) b[j] = Bs[kk][tn * 4 + j];
#pragma unroll
      for (int i = 0; i < 4; i++)
#pragma unroll
        for (int j = 0; j < 4; j++) acc[i * 4 + j] += a[i] * b[j];
    }
    __syncthreads();
  }
#pragma unroll
  for (int i = 0; i < 4; i++) {
    size_t row = (size_t)(bm + tm * 4 + i);
#pragma unroll
    for (int j = 0; j < 4; j++) Co[row * N + bn + tn * 4 + j] = acc[i * 4 + j];
  }
}

// ---------------- causal GQA flash attention (fp32), 32-row Q tiles ----------------
__global__ void attn_k(const float* __restrict__ q, const float* __restrict__ k,
                       const float* __restrict__ v, float* __restrict__ y) {
  int qt = blockIdx.x, head = blockIdx.y;
  int kvh = head / NREPn;
  int q0 = qt * 32;
  int t = threadIdx.x;
  __shared__ float qs[32][Dn + 1];
  __shared__ float ks[32][Dn + 1];
  __shared__ float vs[32][Dn + 1];
  __shared__ float sc[32][33];
  __shared__ float rowm[32], rowl[32], rowa[32];
  const float scale = 0.08838834764831845f;  // 1/sqrt(128)
  for (int e = t; e < 32 * Dn; e += 256) {
    int r = e >> 7, d = e & 127;
    qs[r][d] = q[(size_t)(q0 + r) * (NHn * Dn) + head * Dn + d] * scale;
  }
  if (t < 32) { rowm[t] = -1e30f; rowl[t] = 0.f; }
  float o[16];
#pragma unroll
  for (int j = 0; j < 16; j++) o[j] = 0.f;
  int r = t >> 3;
  int kb = (t & 7) * 4;
  int d0 = (t & 7) * 16;
  __syncthreads();
  for (int kt = 0; kt <= qt; kt++) {
    int kv0 = kt * 32;
    for (int e = t; e < 32 * Dn; e += 256) {
      int rr = e >> 7, d = e & 127;
      size_t off = (size_t)(kv0 + rr) * (NKVn * Dn) + kvh * Dn + d;
      ks[rr][d] = k[off];
      vs[rr][d] = v[off];
    }
    __syncthreads();
#pragma unroll
    for (int j = 0; j < 4; j++) {
      int kk = kb + j;
      float s = 0.f;
      for (int d = 0; d < Dn; d++) s += qs[r][d] * ks[kk][d];
      if (kt == qt && kk > r) s = -1e30f;
      sc[r][kk] = s;
    }
    __syncthreads();
    if (t < 32) {
      int rr = t;
      float mo = rowm[rr];
      float mx = mo;
      for (int kk = 0; kk < 32; kk++) mx = fmaxf(mx, sc[rr][kk]);
      float a = expf(mo - mx);
      float sum = 0.f;
      for (int kk = 0; kk < 32; kk++) {
        float p = expf(sc[rr][kk] - mx);
        sc[rr][kk] = p;
        sum += p;
      }
      rowl[rr] = rowl[rr] * a + sum;
      rowm[rr] = mx;
      rowa[rr] = a;
    }
    __syncthreads();
    float a = rowa[r];
#pragma unroll
    for (int j = 0; j < 16; j++) o[j] *= a;
    for (int kk = 0; kk < 32; kk++) {
      float p = sc[r][kk];
#pragma unroll
      for (int j = 0; j < 16; j++) o[j] += p * vs[kk][d0 + j];
    }
    __syncthreads();
  }
  float inv = 1.f / rowl[r];
#pragma unroll
  for (int j = 0; j < 16; j++)
    y[(size_t)(q0 + r) * (NHn * Dn) + head * Dn + d0 + j] = o[j] * inv;
}

// ---------------- gate logits: gl[n,e] = xf[n] . gate[:,e] ----------------
__global__ void gate_k(const float* __restrict__ xf, const float* __restrict__ g,
                       float* __restrict__ gl) {
  int n = blockIdx.x, t = threadIdx.x;
  int e = t & 7, cs = t >> 3;  // cs in 0..31
  const float* xr = xf + (size_t)n * Cn;
  float s = 0.f;
  for (int j = 0; j < Cn / 32; j++) {
    int c = cs + 32 * j;
    s += xr[c] * g[c * En + e];
  }
  __shared__ float red[256];
  red[t] = s;
  __syncthreads();
  if (t < 8) {
    float tot = 0.f;
    for (int j = 0; j < 32; j++) tot += red[t + 8 * j];
    gl[n * En + t] = tot;
  }
}

// ---------------- routing: softmax + top-2 + per-expert compaction ----------------
__global__ void route_k(const float* __restrict__ gl, float* __restrict__ topw,
                        int* __restrict__ cnt, int* __restrict__ perm) {
  int n = blockIdx.x * blockDim.x + threadIdx.x;
  if (n >= Tn) return;
  float p[En];
  float mx = -1e30f;
#pragma unroll
  for (int e = 0; e < En; e++) { p[e] = gl[n * En + e]; mx = fmaxf(mx, p[e]); }
  float s = 0.f;
#pragma unroll
  for (int e = 0; e < En; e++) { p[e] = expf(p[e] - mx); s += p[e]; }
  float invs = 1.f / s;
#pragma unroll
  for (int e = 0; e < En; e++) p[e] *= invs;
  int i0 = 0;
#pragma unroll
  for (int e = 1; e < En; e++) if (p[e] > p[i0]) i0 = e;
  int i1 = (i0 == 0) ? 1 : 0;
#pragma unroll
  for (int e = 0; e < En; e++) if (e != i0 && p[e] > p[i1]) i1 = e;
  float w0 = p[i0], w1 = p[i1], sw = w0 + w1;
  topw[2 * n]     = w0 / sw;
  topw[2 * n + 1] = w1 / sw;
  int pos0 = atomicAdd(&cnt[i0], 1);
  perm[i0 * Tn + pos0] = 2 * n;
  int pos1 = atomicAdd(&cnt[i1], 1);
  perm[i1 * Tn + pos1] = 2 * n + 1;
}

// ---------------- expert up-proj (gathered rows, dual B, fused SwiGLU) ----------------
__global__ void expert_mm1_k(const float* __restrict__ xf, const float* __restrict__ ew1,
                             const float* __restrict__ ew3, const int* __restrict__ perm,
                             const int* __restrict__ cnt, float* __restrict__ hbuf) {
  int e = blockIdx.z;
  int nrows = cnt[e];
  int bm = blockIdx.x * 64;
  if (bm >= nrows) return;
  int bn = blockIdx.y * 64;
  const float* B1 = ew1 + (size_t)e * Cn * HIDn;
  const float* B3 = ew3 + (size_t)e * Cn * HIDn;
  __shared__ float As[16][65];
  __shared__ float B1s[16][65];
  __shared__ float B3s[16][65];
  __shared__ int prow[64];
  int t = threadIdx.x;
  if (t < 64) {
    int i = bm + t;
    prow[t] = (i < nrows) ? perm[e * Tn + i] : -1;
  }
  __syncthreads();
  int tm = t >> 4, tn = t & 15;
  int lr = t >> 4, lk = t & 15;
  int lbk = t >> 6, lbn = t & 63;
  float acc1[16], acc3[16];
#pragma unroll
  for (int i = 0; i < 16; i++) { acc1[i] = 0.f; acc3[i] = 0.f; }
  for (int k0 = 0; k0 < Cn; k0 += 16) {
#pragma unroll
    for (int i = 0; i < 4; i++) {
      int m = lr + 16 * i;
      int p = prow[m];
      As[lk][m] = (p >= 0) ? xf[(size_t)(p >> 1) * Cn + k0 + lk] : 0.f;
    }
#pragma unroll
    for (int i = 0; i < 4; i++) {
      size_t off = (size_t)(k0 + lbk + 4 * i) * HIDn + bn + lbn;
      B1s[lbk + 4 * i][lbn] = B1[off];
      B3s[lbk + 4 * i][lbn] = B3[off];
    }
    __syncthreads();
#pragma unroll
    for (int kk = 0; kk < 16; kk++) {
      float a[4], b1[4], b3[4];
#pragma unroll
      for (int i = 0; i < 4; i++) a[i] = As[kk][tm * 4 + i];
#pragma unroll
      for (int j = 0; j < 4; j++) { b1[j] = B1s[kk][tn * 4 + j]; b3[j] = B3s[kk][tn * 4 + j]; }
#pragma unroll
      for (int i = 0; i < 4; i++)
#pragma unroll
        for (int j = 0; j < 4; j++) {
          acc1[i * 4 + j] += a[i] * b1[j];
          acc3[i * 4 + j] += a[i] * b3[j];
        }
    }
    __syncthreads();
  }
#pragma unroll
  for (int i = 0; i < 4; i++) {
    int m = tm * 4 + i;
    int p = prow[m];
    if (p < 0) continue;
#pragma unroll
    for (int j = 0; j < 4; j++) {
      float h1 = acc1[i * 4 + j], h3 = acc3[i * 4 + j];
      float sig = 1.f / (1.f + expf(-h1));
      hbuf[(size_t)p * HIDn + bn + tn * 4 + j] = h1 * sig * h3;
    }
  }
}

// ---------------- expert down-proj (gathered rows) ----------------
__global__ void expert_mm2_k(const float* __restrict__ hbuf, const float* __restrict__ ew2,
                             const int* __restrict__ perm, const int* __restrict__ cnt,
                             float* __restrict__ pairout) {
  int e = blockIdx.z;
  int nrows = cnt[e];
  int bm = blockIdx.x * 64;
  if (bm >= nrows) return;
  int bn = blockIdx.y * 64;
  const float* B = ew2 + (size_t)e * HIDn * Cn;
  __shared__ float As[16][65];
  __shared__ float Bs[16][65];
  __shared__ int prow[64];
  int t = threadIdx.x;
  if (t < 64) {
    int i = bm + t;
    prow[t] = (i < nrows) ? perm[e * Tn + i] : -1;
  }
  __syncthreads();
  int tm = t >> 4, tn = t & 15;
  int lr = t >> 4, lk = t & 15;
  int lbk = t >> 6, lbn = t & 63;
  float acc[16];
#pragma unroll
  for (int i = 0; i < 16; i++) acc[i] = 0.f;
  for (int k0 = 0; k0 < HIDn; k0 += 16) {
#pragma unroll
    for (int i = 0; i < 4; i++) {
      int m = lr + 16 * i;
      int p = prow[m];
      As[lk][m] = (p >= 0) ? hbuf[(size_t)p * HIDn + k0 + lk] : 0.f;
    }
#pragma unroll
    for (int i = 0; i < 4; i++)
      Bs[lbk + 4 * i][lbn] = B[(size_t)(k0 + lbk + 4 * i) * Cn + bn + lbn];
    __syncthreads();
#pragma unroll
    for (int kk = 0; kk < 16; kk++) {
      float a[4], b[4];
#pragma unroll
      for (int i = 0; i < 4; i++) a[i] = As[kk][tm * 4 + i];
#pragma unroll
      for (int j = 0; j < 4; j++) b[j] = Bs[kk][tn * 4 + j];
#pragma unroll
      for (int i = 0; i < 4; i++)
#pragma unroll
        for (int j = 0; j < 4; j++) acc[i * 4 + j] += a[i] * b[j];
    }
    __syncthreads();
  }
#pragma unroll
  for (int i = 0; i < 4; i++) {
    int m = tm * 4 + i;
    int p = prow[m];
    if (p < 0) continue;
#pragma unroll
    for (int j = 0; j < 4; j++)
      pairout[(size_t)p * Cn + bn + tn * 4 + j] = acc[i * 4 + j];
  }
}

// ---------------- combine: x += w0*pair0 + w1*pair1 ----------------
__global__ void combine_k(const float* __restrict__ pairout, const float* __restrict__ topw,
                          float* __restrict__ x) {
  int n = blockIdx.x, t = threadIdx.x;
  float w0 = topw[2 * n], w1 = topw[2 * n + 1];
  const float* p0 = pairout + (size_t)(2 * n) * Cn;
  const float* p1 = pairout + (size_t)(2 * n + 1) * Cn;
  float* xr = x + (size_t)n * Cn;
  for (int c = t; c < Cn; c += 256) xr[c] += w0 * p0[c] + w1 * p1[c];
}

extern "C" void kernel_launch(void* const* d_in, const int* in_sizes, int n_in,
                              void* d_out, int out_size, void* d_ws, size_t ws_size,
                              hipStream_t stream) {
  const int*   tokens = (const int*)d_in[0];
  const float* emb    = (const float*)d_in[1];
  const float* pos    = (const float*)d_in[2];
  const float* wq     = (const float*)d_in[3];
  const float* wk     = (const float*)d_in[4];
  const float* wv     = (const float*)d_in[5];
  const float* wo     = (const float*)d_in[6];
  const float* attn_nw= (const float*)d_in[7];
  const float* ffn_nw = (const float*)d_in[8];
  const float* gate   = (const float*)d_in[9];
  const float* ew1    = (const float*)d_in[10];
  const float* ew2    = (const float*)d_in[11];
  const float* ew3    = (const float*)d_in[12];
  const float* final_nw = (const float*)d_in[13];
  float* out = (float*)d_out;

  float* ws = (float*)d_ws;
  const size_t NC = (size_t)Tn * Cn;          // 3,145,728
  float* x       = ws;                         size_t off = NC;
  float* h       = ws + off;                   off += NC;
  float* qb      = ws + off;                   off += NC;
  float* kb      = ws + off;                   off += (size_t)Tn * NKVn * Dn;
  float* vb      = ws + off;                   off += (size_t)Tn * NKVn * Dn;
  float* yb      = ws + off;                   off += NC;
  float* gl      = ws + off;                   off += (size_t)Tn * En;
  float* topw    = ws + off;                   off += (size_t)Tn * Kn;
  float* hbuf    = ws + off;                   off += (size_t)Tn * Kn * HIDn;
  float* pairout = ws + off;                   off += (size_t)Tn * Kn * Cn;
  int* cnt  = (int*)(ws + off);                off += 16;
  int* perm = (int*)(ws + off);                off += (size_t)En * Tn;

  embed_k<<<Tn, 256, 0, stream>>>(tokens, emb, pos, x);

  for (int l = 0; l < Ln; l++) {
    const float* wq_l = wq + (size_t)l * Cn * (NHn * Dn);
    const float* wk_l = wk + (size_t)l * Cn * (NKVn * Dn);
    const float* wv_l = wv + (size_t)l * Cn * (NKVn * Dn);
    const float* wo_l = wo + (size_t)l * Cn * Cn;
    const float* g_l  = gate + (size_t)l * Cn * En;
    const float* e1_l = ew1 + (size_t)l * En * Cn * HIDn;
    const float* e2_l = ew2 + (size_t)l * En * HIDn * Cn;
    const float* e3_l = ew3 + (size_t)l * En * Cn * HIDn;

    // --- attention ---
    rmsnorm_k<<<Tn, 256, 0, stream>>>(x, attn_nw + (size_t)l * Cn, h);
    gemm_nn_k<<<dim3(Tn / 64, (NHn * Dn) / 64), 256, 0, stream>>>(h, wq_l, nullptr, qb, Tn, NHn * Dn, Cn);
    gemm_nn_k<<<dim3(Tn / 64, (NKVn * Dn) / 64), 256, 0, stream>>>(h, wk_l, nullptr, kb, Tn, NKVn * Dn, Cn);
    gemm_nn_k<<<dim3(Tn / 64, (NKVn * Dn) / 64), 256, 0, stream>>>(h, wv_l, nullptr, vb, Tn, NKVn * Dn, Cn);
    attn_k<<<dim3(Tn / 32, NHn), 256, 0, stream>>>(qb, kb, vb, yb);
    gemm_nn_k<<<dim3(Tn / 64, Cn / 64), 256, 0, stream>>>(yb, wo_l, x, x, Tn, Cn, Cn);

    // --- MoE FFN ---
    rmsnorm_k<<<Tn, 256, 0, stream>>>(x, ffn_nw + (size_t)l * Cn, h);
    gate_k<<<Tn, 256, 0, stream>>>(h, g_l, gl);
    hipMemsetAsync(cnt, 0, 16 * sizeof(int), stream);
    route_k<<<Tn / 256, 256, 0, stream>>>(gl, topw, cnt, perm);
    expert_mm1_k<<<dim3(Tn / 64, HIDn / 64, En), 256, 0, stream>>>(h, e1_l, e3_l, perm, cnt, hbuf);
    expert_mm2_k<<<dim3(Tn / 64, Cn / 64, En), 256, 0, stream>>>(hbuf, e2_l, perm, cnt, pairout);
    combine_k<<<Tn, 256, 0, stream>>>(pairout, topw, x);
  }

  // --- final norm + tied logits ---
  rmsnorm_k<<<Tn, 256, 0, stream>>>(x, final_nw, h);
  gemm_nt_k<<<dim3(Tn / 64, Vn / 64), 256, 0, stream>>>(h, emb, out, Tn, Vn, Cn);
}

// Round 5
// 20663.853 us; speedup vs baseline: 1.1890x; 1.1890x over previous
//
#include <hip/hip_runtime.h>
#include <hip/hip_bf16.h>
#include <math.h>

#define Tn   2048
#define Cn   1536
#define Vn   32000
#define NHn  12
#define NKVn 4
#define Dn   128
#define HIDn 2048
#define En   8
#define Kn   2
#define Ln   2
#define NREPn 3
#define EPSn 1e-6f

using bf16 = __hip_bfloat16;
using bf16x8 = __attribute__((ext_vector_type(8))) short;
using f32x4v = __attribute__((ext_vector_type(4))) float;

// ---------------- embed: x = emb[tok] + pos ----------------
__global__ void embed_k(const int* __restrict__ tok, const float* __restrict__ emb,
                        const float* __restrict__ pos, float* __restrict__ x) {
  int n = blockIdx.x;
  int t = threadIdx.x;
  int id = tok[n];
  const float* er = emb + (size_t)id * Cn;
  const float* pr = pos + (size_t)n * Cn;
  float* xr = x + (size_t)n * Cn;
  for (int c = t; c < Cn; c += 256) xr[c] = er[c] + pr[c];
}

// ---------------- RMSNorm (round-1 exact) ----------------
__global__ void rmsnorm_k(const float* __restrict__ x, const float* __restrict__ w,
                          float* __restrict__ out) {
  int n = blockIdx.x, t = threadIdx.x;
  const float* xr = x + (size_t)n * Cn;
  float v[6];
  float ss = 0.f;
#pragma unroll
  for (int i = 0; i < 6; i++) { v[i] = xr[t + i * 256]; ss += v[i] * v[i]; }
  for (int off = 32; off > 0; off >>= 1) ss += __shfl_down(ss, off, 64);
  __shared__ float red[4];
  __shared__ float rtot;
  int wave = t >> 6, lane = t & 63;
  if (lane == 0) red[wave] = ss;
  __syncthreads();
  if (t == 0) rtot = rsqrtf((red[0] + red[1] + red[2] + red[3]) / (float)Cn + EPSn);
  __syncthreads();
  float r = rtot;
  float* orow = out + (size_t)n * Cn;
#pragma unroll
  for (int i = 0; i < 6; i++) { int c = t + i * 256; orow[c] = v[i] * r * w[c]; }
}

// ---------------- flat fp32 -> bf16 convert ----------------
__global__ void f2b_k(const float* __restrict__ s, bf16* __restrict__ d, size_t n4) {
  size_t i = (size_t)blockIdx.x * 256 + threadIdx.x;
  size_t stride = (size_t)gridDim.x * 256;
  for (; i < n4; i += stride) {
    float4 v = ((const float4*)s)[i];
    d[i * 4 + 0] = __float2bfloat16(v.x);
    d[i * 4 + 1] = __float2bfloat16(v.y);
    d[i * 4 + 2] = __float2bfloat16(v.z);
    d[i * 4 + 3] = __float2bfloat16(v.w);
  }
}

// ---------------- MFMA GEMM under test: C f32 = A bf16 @ Bt bf16^T ----------------
// Direct-global fragments (round-4 version). Only used for the final logits GEMM.
__global__ void __launch_bounds__(256) gemm_bt(const bf16* __restrict__ A, const bf16* __restrict__ Bt,
                                               const float* res, float* Co, int M, int N, int K) {
  int t = threadIdx.x;
  int l = t & 63, w = t >> 6;
  int bm = blockIdx.x * 128, bn = blockIdx.y * 128;
  int wr = (w >> 1) * 64, wc = (w & 1) * 64;
  const f32x4v zero = {0.f, 0.f, 0.f, 0.f};
  f32x4v acc[4][4];
#pragma unroll
  for (int i = 0; i < 4; i++)
#pragma unroll
    for (int j = 0; j < 4; j++) acc[i][j] = zero;
  int rl = l & 15, ko = (l >> 4) * 8;
  const bf16* arow[4];
  const bf16* brow[4];
#pragma unroll
  for (int i = 0; i < 4; i++) arow[i] = A + (size_t)(bm + wr + i * 16 + rl) * K + ko;
#pragma unroll
  for (int j = 0; j < 4; j++) brow[j] = Bt + (size_t)(bn + wc + j * 16 + rl) * K + ko;
  for (int k0 = 0; k0 < K; k0 += 32) {
    bf16x8 a[4], b[4];
#pragma unroll
    for (int i = 0; i < 4; i++) a[i] = *(const bf16x8*)(arow[i] + k0);
#pragma unroll
    for (int j = 0; j < 4; j++) b[j] = *(const bf16x8*)(brow[j] + k0);
#pragma unroll
    for (int i = 0; i < 4; i++)
#pragma unroll
      for (int j = 0; j < 4; j++)
        acc[i][j] = __builtin_amdgcn_mfma_f32_16x16x32_bf16(a[i], b[j], acc[i][j], 0, 0, 0);
  }
#pragma unroll
  for (int i = 0; i < 4; i++) {
    int rbase = bm + wr + i * 16 + (l >> 4) * 4;
#pragma unroll
    for (int j = 0; j < 4; j++) {
      int col = bn + wc + j * 16 + (l & 15);
#pragma unroll
      for (int r = 0; r < 4; r++) {
        size_t idx = (size_t)(rbase + r) * N + col;
        float v = acc[i][j][r];
        if (res) v += res[idx];
        Co[idx] = v;
      }
    }
  }
}

// ---------------- fp32 GEMM: C = A[M,K] @ B[K,N] (+res)  (round-1 exact) ----------------
__global__ void gemm_nn_k(const float* __restrict__ A, const float* __restrict__ B,
                          const float* __restrict__ res, float* __restrict__ Co,
                          int M, int N, int K) {
  __shared__ float As[16][65];
  __shared__ float Bs[16][65];
  int t = threadIdx.x;
  int bm = blockIdx.x * 64, bn = blockIdx.y * 64;
  int tm = t >> 4, tn = t & 15;
  int lr = t >> 4, lk = t & 15;
  int lbk = t >> 6, lbn = t & 63;
  float acc[16];
#pragma unroll
  for (int i = 0; i < 16; i++) acc[i] = 0.f;
  for (int k0 = 0; k0 < K; k0 += 16) {
#pragma unroll
    for (int i = 0; i < 4; i++)
      As[lk][lr + 16 * i] = A[(size_t)(bm + lr + 16 * i) * K + k0 + lk];
#pragma unroll
    for (int i = 0; i < 4; i++)
      Bs[lbk + 4 * i][lbn] = B[(size_t)(k0 + lbk + 4 * i) * N + bn + lbn];
    __syncthreads();
#pragma unroll
    for (int kk = 0; kk < 16; kk++) {
      float a[4], b[4];
#pragma unroll
      for (int i = 0; i < 4; i++) a[i] = As[kk][tm * 4 + i];
#pragma unroll
      for (int j = 0; j < 4; j++) b[j] = Bs[kk][tn * 4 + j];
#pragma unroll
      for (int i = 0; i < 4; i++)
#pragma unroll
        for (int j = 0; j < 4; j++) acc[i * 4 + j] += a[i] * b[j];
    }
    __syncthreads();
  }
#pragma unroll
  for (int i = 0; i < 4; i++) {
    size_t row = (size_t)(bm + tm * 4 + i);
#pragma unroll
    for (int j = 0; j < 4; j++) {
      size_t idx = row * N + bn + tn * 4 + j;
      float vv = acc[i * 4 + j];
      if (res) vv += res[idx];
      Co[idx] = vv;
    }
  }
}

// ---------------- fp32 GEMM B^T (round-1 exact, fallback logits) ----------------
__global__ void gemm_nt_k(const float* __restrict__ A, const float* __restrict__ Bt,
                          float* __restrict__ Co, int M, int N, int K) {
  __shared__ float As[16][65];
  __shared__ float Bs[16][65];
  int t = threadIdx.x;
  int bm = blockIdx.x * 64, bn = blockIdx.y * 64;
  int tm = t >> 4, tn = t & 15;
  int lr = t >> 4, lk = t & 15;
  float acc[16];
#pragma unroll
  for (int i = 0; i < 16; i++) acc[i] = 0.f;
  for (int k0 = 0; k0 < K; k0 += 16) {
#pragma unroll
    for (int i = 0; i < 4; i++)
      As[lk][lr + 16 * i] = A[(size_t)(bm + lr + 16 * i) * K + k0 + lk];
#pragma unroll
    for (int i = 0; i < 4; i++)
      Bs[lk][lr + 16 * i] = Bt[(size_t)(bn + lr + 16 * i) * K + k0 + lk];
    __syncthreads();
#pragma unroll
    for (int kk = 0; kk < 16; kk++) {
      float a[4], b[4];
#pragma unroll
      for (int i = 0; i < 4; i++) a[i] = As[kk][tm * 4 + i];
#pragma unroll
      for (int j = 0; j < 4; j++) b[j] = Bs[kk][tn * 4 + j];
#pragma unroll
      for (int i = 0; i < 4; i++)
#pragma unroll
        for (int j = 0; j < 4; j++) acc[i * 4 + j] += a[i] * b[j];
    }
    __syncthreads();
  }
#pragma unroll
  for (int i = 0; i < 4; i++) {
    size_t row = (size_t)(bm + tm * 4 + i);
#pragma unroll
    for (int j = 0; j < 4; j++) Co[row * N + bn + tn * 4 + j] = acc[i * 4 + j];
  }
}

// ---------------- causal GQA flash attention fp32 (round-1 exact) ----------------
__global__ void attn_f32_k(const float* __restrict__ q, const float* __restrict__ k,
                           const float* __restrict__ v, float* __restrict__ y) {
  int qt = blockIdx.x, head = blockIdx.y;
  int kvh = head / NREPn;
  int q0 = qt * 32;
  int t = threadIdx.x;
  __shared__ float qs[32][Dn + 1];
  __shared__ float ks[32][Dn + 1];
  __shared__ float vs[32][Dn + 1];
  __shared__ float sc[32][33];
  __shared__ float rowm[32], rowl[32], rowa[32];
  const float scale = 0.08838834764831845f;
  for (int e = t; e < 32 * Dn; e += 256) {
    int r = e >> 7, d = e & 127;
    qs[r][d] = q[(size_t)(q0 + r) * (NHn * Dn) + head * Dn + d] * scale;
  }
  if (t < 32) { rowm[t] = -1e30f; rowl[t] = 0.f; }
  float o[16];
#pragma unroll
  for (int j = 0; j < 16; j++) o[j] = 0.f;
  int r = t >> 3;
  int kb = (t & 7) * 4;
  int d0 = (t & 7) * 16;
  __syncthreads();
  for (int kt = 0; kt <= qt; kt++) {
    int kv0 = kt * 32;
    for (int e = t; e < 32 * Dn; e += 256) {
      int rr = e >> 7, d = e & 127;
      size_t off = (size_t)(kv0 + rr) * (NKVn * Dn) + kvh * Dn + d;
      ks[rr][d] = k[off];
      vs[rr][d] = v[off];
    }
    __syncthreads();
#pragma unroll
    for (int j = 0; j < 4; j++) {
      int kk = kb + j;
      float s = 0.f;
      for (int d = 0; d < Dn; d++) s += qs[r][d] * ks[kk][d];
      if (kt == qt && kk > r) s = -1e30f;
      sc[r][kk] = s;
    }
    __syncthreads();
    if (t < 32) {
      int rr = t;
      float mo = rowm[rr];
      float mx = mo;
      for (int kk = 0; kk < 32; kk++) mx = fmaxf(mx, sc[rr][kk]);
      float a = expf(mo - mx);
      float sum = 0.f;
      for (int kk = 0; kk < 32; kk++) {
        float p = expf(sc[rr][kk] - mx);
        sc[rr][kk] = p;
        sum += p;
      }
      rowl[rr] = rowl[rr] * a + sum;
      rowm[rr] = mx;
      rowa[rr] = a;
    }
    __syncthreads();
    float a = rowa[r];
#pragma unroll
    for (int j = 0; j < 16; j++) o[j] *= a;
    for (int kk = 0; kk < 32; kk++) {
      float p = sc[r][kk];
#pragma unroll
      for (int j = 0; j < 16; j++) o[j] += p * vs[kk][d0 + j];
    }
    __syncthreads();
  }
  float inv = 1.f / rowl[r];
#pragma unroll
  for (int j = 0; j < 16; j++)
    y[(size_t)(q0 + r) * (NHn * Dn) + head * Dn + d0 + j] = o[j] * inv;
}

// ---------------- gate logits (round-1 exact) ----------------
__global__ void gate_k(const float* __restrict__ xf, const float* __restrict__ g,
                       float* __restrict__ gl) {
  int n = blockIdx.x, t = threadIdx.x;
  int e = t & 7, cs = t >> 3;
  const float* xr = xf + (size_t)n * Cn;
  float s = 0.f;
  for (int j = 0; j < Cn / 32; j++) {
    int c = cs + 32 * j;
    s += xr[c] * g[c * En + e];
  }
  __shared__ float red[256];
  red[t] = s;
  __syncthreads();
  if (t < 8) {
    float tot = 0.f;
    for (int j = 0; j < 32; j++) tot += red[t + 8 * j];
    gl[n * En + t] = tot;
  }
}

// ---------------- routing (round-1 exact, Tn stride) ----------------
__global__ void route_k(const float* __restrict__ gl, float* __restrict__ topw,
                        int* __restrict__ cnt, int* __restrict__ perm) {
  int n = blockIdx.x * blockDim.x + threadIdx.x;
  if (n >= Tn) return;
  float p[En];
  float mx = -1e30f;
#pragma unroll
  for (int e = 0; e < En; e++) { p[e] = gl[n * En + e]; mx = fmaxf(mx, p[e]); }
  float s = 0.f;
#pragma unroll
  for (int e = 0; e < En; e++) { p[e] = expf(p[e] - mx); s += p[e]; }
  float invs = 1.f / s;
#pragma unroll
  for (int e = 0; e < En; e++) p[e] *= invs;
  int i0 = 0;
#pragma unroll
  for (int e = 1; e < En; e++) if (p[e] > p[i0]) i0 = e;
  int i1 = (i0 == 0) ? 1 : 0;
#pragma unroll
  for (int e = 0; e < En; e++) if (e != i0 && p[e] > p[i1]) i1 = e;
  float w0 = p[i0], w1 = p[i1], sw = w0 + w1;
  topw[2 * n]     = w0 / sw;
  topw[2 * n + 1] = w1 / sw;
  int pos0 = atomicAdd(&cnt[i0], 1);
  perm[i0 * Tn + pos0] = 2 * n;
  int pos1 = atomicAdd(&cnt[i1], 1);
  perm[i1 * Tn + pos1] = 2 * n + 1;
}

// ---------------- expert up-proj fp32 (round-1 exact, Tn stride) ----------------
__global__ void expert_mm1_k(const float* __restrict__ xf, const float* __restrict__ ew1,
                             const float* __restrict__ ew3, const int* __restrict__ perm,
                             const int* __restrict__ cnt, float* __restrict__ hbuf) {
  int e = blockIdx.z;
  int nrows = cnt[e];
  int bm = blockIdx.x * 64;
  if (bm >= nrows) return;
  int bn = blockIdx.y * 64;
  const float* B1 = ew1 + (size_t)e * Cn * HIDn;
  const float* B3 = ew3 + (size_t)e * Cn * HIDn;
  __shared__ float As[16][65];
  __shared__ float B1s[16][65];
  __shared__ float B3s[16][65];
  __shared__ int prow[64];
  int t = threadIdx.x;
  if (t < 64) {
    int i = bm + t;
    prow[t] = (i < nrows) ? perm[e * Tn + i] : -1;
  }
  __syncthreads();
  int tm = t >> 4, tn = t & 15;
  int lr = t >> 4, lk = t & 15;
  int lbk = t >> 6, lbn = t & 63;
  float acc1[16], acc3[16];
#pragma unroll
  for (int i = 0; i < 16; i++) { acc1[i] = 0.f; acc3[i] = 0.f; }
  for (int k0 = 0; k0 < Cn; k0 += 16) {
#pragma unroll
    for (int i = 0; i < 4; i++) {
      int m = lr + 16 * i;
      int p = prow[m];
      As[lk][m] = (p >= 0) ? xf[(size_t)(p >> 1) * Cn + k0 + lk] : 0.f;
    }
#pragma unroll
    for (int i = 0; i < 4; i++) {
      size_t off = (size_t)(k0 + lbk + 4 * i) * HIDn + bn + lbn;
      B1s[lbk + 4 * i][lbn] = B1[off];
      B3s[lbk + 4 * i][lbn] = B3[off];
    }
    __syncthreads();
#pragma unroll
    for (int kk = 0; kk < 16; kk++) {
      float a[4], b1[4], b3[4];
#pragma unroll
      for (int i = 0; i < 4; i++) a[i] = As[kk][tm * 4 + i];
#pragma unroll
      for (int j = 0; j < 4; j++) { b1[j] = B1s[kk][tn * 4 + j]; b3[j] = B3s[kk][tn * 4 + j]; }
#pragma unroll
      for (int i = 0; i < 4; i++)
#pragma unroll
        for (int j = 0; j < 4; j++) {
          acc1[i * 4 + j] += a[i] * b1[j];
          acc3[i * 4 + j] += a[i] * b3[j];
        }
    }
    __syncthreads();
  }
#pragma unroll
  for (int i = 0; i < 4; i++) {
    int m = tm * 4 + i;
    int p = prow[m];
    if (p < 0) continue;
#pragma unroll
    for (int j = 0; j < 4; j++) {
      float h1 = acc1[i * 4 + j], h3 = acc3[i * 4 + j];
      float sig = 1.f / (1.f + expf(-h1));
      hbuf[(size_t)p * HIDn + bn + tn * 4 + j] = h1 * sig * h3;
    }
  }
}

// ---------------- expert down-proj fp32 (round-1 exact, Tn stride) ----------------
__global__ void expert_mm2_k(const float* __restrict__ hbuf, const float* __restrict__ ew2,
                             const int* __restrict__ perm, const int* __restrict__ cnt,
                             float* __restrict__ pairout) {
  int e = blockIdx.z;
  int nrows = cnt[e];
  int bm = blockIdx.x * 64;
  if (bm >= nrows) return;
  int bn = blockIdx.y * 64;
  const float* B = ew2 + (size_t)e * HIDn * Cn;
  __shared__ float As[16][65];
  __shared__ float Bs[16][65];
  __shared__ int prow[64];
  int t = threadIdx.x;
  if (t < 64) {
    int i = bm + t;
    prow[t] = (i < nrows) ? perm[e * Tn + i] : -1;
  }
  __syncthreads();
  int tm = t >> 4, tn = t & 15;
  int lr = t >> 4, lk = t & 15;
  int lbk = t >> 6, lbn = t & 63;
  float acc[16];
#pragma unroll
  for (int i = 0; i < 16; i++) acc[i] = 0.f;
  for (int k0 = 0; k0 < HIDn; k0 += 16) {
#pragma unroll
    for (int i = 0; i < 4; i++) {
      int m = lr + 16 * i;
      int p = prow[m];
      As[lk][m] = (p >= 0) ? hbuf[(size_t)p * HIDn + k0 + lk] : 0.f;
    }
#pragma unroll
    for (int i = 0; i < 4; i++)
      Bs[lbk + 4 * i][lbn] = B[(size_t)(k0 + lbk + 4 * i) * Cn + bn + lbn];
    __syncthreads();
#pragma unroll
    for (int kk = 0; kk < 16; kk++) {
      float a[4], b[4];
#pragma unroll
      for (int i = 0; i < 4; i++) a[i] = As[kk][tm * 4 + i];
#pragma unroll
      for (int j = 0; j < 4; j++) b[j] = Bs[kk][tn * 4 + j];
#pragma unroll
      for (int i = 0; i < 4; i++)
#pragma unroll
        for (int j = 0; j < 4; j++) acc[i * 4 + j] += a[i] * b[j];
    }
    __syncthreads();
  }
#pragma unroll
  for (int i = 0; i < 4; i++) {
    int m = tm * 4 + i;
    int p = prow[m];
    if (p < 0) continue;
#pragma unroll
    for (int j = 0; j < 4; j++)
      pairout[(size_t)p * Cn + bn + tn * 4 + j] = acc[i * 4 + j];
  }
}

// ---------------- combine (round-1 exact) ----------------
__global__ void combine_k(const float* __restrict__ pairout, const float* __restrict__ topw,
                          float* __restrict__ x) {
  int n = blockIdx.x, t = threadIdx.x;
  float w0 = topw[2 * n], w1 = topw[2 * n + 1];
  const float* p0 = pairout + (size_t)(2 * n) * Cn;
  const float* p1 = pairout + (size_t)(2 * n + 1) * Cn;
  float* xr = x + (size_t)n * Cn;
  for (int c = t; c < Cn; c += 256) xr[c] += w0 * p0[c] + w1 * p1[c];
}

// =================================================================================
extern "C" void kernel_launch(void* const* d_in, const int* in_sizes, int n_in,
                              void* d_out, int out_size, void* d_ws, size_t ws_size,
                              hipStream_t stream) {
  const int*   tokens = (const int*)d_in[0];
  const float* emb    = (const float*)d_in[1];
  const float* pos    = (const float*)d_in[2];
  const float* wq     = (const float*)d_in[3];
  const float* wk     = (const float*)d_in[4];
  const float* wv     = (const float*)d_in[5];
  const float* wo     = (const float*)d_in[6];
  const float* attn_nw= (const float*)d_in[7];
  const float* ffn_nw = (const float*)d_in[8];
  const float* gate   = (const float*)d_in[9];
  const float* ew1    = (const float*)d_in[10];
  const float* ew2    = (const float*)d_in[11];
  const float* ew3    = (const float*)d_in[12];
  const float* final_nw = (const float*)d_in[13];
  float* out = (float*)d_out;

  char* wsb = (char*)d_ws;
  const size_t NC = (size_t)Tn * Cn;

  // --- layout A (debug: round-1 + bf16 logits tail). hb before the pool; embB
  //     aliases the pool (all pool buffers dead by the time f2b writes it). ---
  size_t off = 0;
  auto alloc = [&](size_t bytes) -> size_t {
    off = (off + 255) & ~(size_t)255;
    size_t p = off;
    off += bytes;
    return p;
  };
  size_t o_x    = alloc(NC * 4);
  size_t o_h    = alloc(NC * 4);
  size_t o_hb   = alloc(NC * 2);
  size_t o_pool = off;
  size_t o_qb   = alloc(NC * 4);
  size_t o_kb   = alloc((size_t)Tn * NKVn * Dn * 4);
  size_t o_vb   = alloc((size_t)Tn * NKVn * Dn * 4);
  size_t o_yb   = alloc(NC * 4);
  size_t o_gl   = alloc((size_t)Tn * En * 4);
  size_t o_topw = alloc((size_t)Tn * Kn * 4);
  size_t o_hbuf = alloc((size_t)Tn * Kn * HIDn * 4);
  size_t o_pair = alloc((size_t)Tn * Kn * Cn * 4);
  size_t o_cnt  = alloc(64);
  size_t o_perm = alloc((size_t)En * Tn * 4);
  size_t embB_bytes = (size_t)Vn * Cn * 2;
  if (off - o_pool < embB_bytes) off = o_pool + embB_bytes;  // extend pool for embB
  size_t need_debug = off;
  bool dbg = (ws_size >= need_debug);

  if (!dbg) {
    // --- layout B: exact round-1 (no hb, no pool extension) ---
    off = 0;
    o_x    = alloc(NC * 4);
    o_h    = alloc(NC * 4);
    o_qb   = alloc(NC * 4);
    o_kb   = alloc((size_t)Tn * NKVn * Dn * 4);
    o_vb   = alloc((size_t)Tn * NKVn * Dn * 4);
    o_yb   = alloc(NC * 4);
    o_gl   = alloc((size_t)Tn * En * 4);
    o_topw = alloc((size_t)Tn * Kn * 4);
    o_hbuf = alloc((size_t)Tn * Kn * HIDn * 4);
    o_pair = alloc((size_t)Tn * Kn * Cn * 4);
    o_cnt  = alloc(64);
    o_perm = alloc((size_t)En * Tn * 4);
  }

  float* x       = (float*)(wsb + o_x);
  float* h       = (float*)(wsb + o_h);
  float* qb      = (float*)(wsb + o_qb);
  float* kb      = (float*)(wsb + o_kb);
  float* vb      = (float*)(wsb + o_vb);
  float* yb      = (float*)(wsb + o_yb);
  float* gl      = (float*)(wsb + o_gl);
  float* topw    = (float*)(wsb + o_topw);
  float* hbuf    = (float*)(wsb + o_hbuf);
  float* pairout = (float*)(wsb + o_pair);
  int*   cnt     = (int*)(wsb + o_cnt);
  int*   perm    = (int*)(wsb + o_perm);
  bf16*  hb      = dbg ? (bf16*)(wsb + o_hb) : nullptr;
  bf16*  embB    = dbg ? (bf16*)(wsb + o_pool) : nullptr;

  // ---------- round-1 fp32 pipeline (proven) ----------
  embed_k<<<Tn, 256, 0, stream>>>(tokens, emb, pos, x);
  for (int l = 0; l < Ln; l++) {
    const float* wq_l = wq + (size_t)l * Cn * (NHn * Dn);
    const float* wk_l = wk + (size_t)l * Cn * (NKVn * Dn);
    const float* wv_l = wv + (size_t)l * Cn * (NKVn * Dn);
    const float* wo_l = wo + (size_t)l * Cn * Cn;
    const float* g_l  = gate + (size_t)l * Cn * En;
    const float* e1_l = ew1 + (size_t)l * En * Cn * HIDn;
    const float* e2_l = ew2 + (size_t)l * En * HIDn * Cn;
    const float* e3_l = ew3 + (size_t)l * En * Cn * HIDn;
    rmsnorm_k<<<Tn, 256, 0, stream>>>(x, attn_nw + (size_t)l * Cn, h);
    gemm_nn_k<<<dim3(Tn / 64, (NHn * Dn) / 64), 256, 0, stream>>>(h, wq_l, nullptr, qb, Tn, NHn * Dn, Cn);
    gemm_nn_k<<<dim3(Tn / 64, (NKVn * Dn) / 64), 256, 0, stream>>>(h, wk_l, nullptr, kb, Tn, NKVn * Dn, Cn);
    gemm_nn_k<<<dim3(Tn / 64, (NKVn * Dn) / 64), 256, 0, stream>>>(h, wv_l, nullptr, vb, Tn, NKVn * Dn, Cn);
    attn_f32_k<<<dim3(Tn / 32, NHn), 256, 0, stream>>>(qb, kb, vb, yb);
    gemm_nn_k<<<dim3(Tn / 64, Cn / 64), 256, 0, stream>>>(yb, wo_l, x, x, Tn, Cn, Cn);
    rmsnorm_k<<<Tn, 256, 0, stream>>>(x, ffn_nw + (size_t)l * Cn, h);
    gate_k<<<Tn, 256, 0, stream>>>(h, g_l, gl);
    hipMemsetAsync(cnt, 0, 64, stream);
    route_k<<<Tn / 256, 256, 0, stream>>>(gl, topw, cnt, perm);
    expert_mm1_k<<<dim3(Tn / 64, HIDn / 64, En), 256, 0, stream>>>(h, e1_l, e3_l, perm, cnt, hbuf);
    expert_mm2_k<<<dim3(Tn / 64, Cn / 64, En), 256, 0, stream>>>(hbuf, e2_l, perm, cnt, pairout);
    combine_k<<<Tn, 256, 0, stream>>>(pairout, topw, x);
  }
  rmsnorm_k<<<Tn, 256, 0, stream>>>(x, final_nw, h);

  if (dbg) {
    // ---------- bf16 MFMA logits tail (the experiment) ----------
    f2b_k<<<2048, 256, 0, stream>>>(h, hb, NC / 4);
    f2b_k<<<2048, 256, 0, stream>>>(emb, embB, (size_t)Vn * Cn / 4);
    gemm_bt<<<dim3(Tn / 128, Vn / 128), 256, 0, stream>>>(hb, embB, nullptr, out, Tn, Vn, Cn);
  } else {
    // ---------- round-1 fp32 logits tail ----------
    gemm_nt_k<<<dim3(Tn / 64, Vn / 64), 256, 0, stream>>>(h, emb, out, Tn, Vn, Cn);
  }
}

// Round 8
// 16072.603 us; speedup vs baseline: 1.5286x; 1.2857x over previous
//
#include <hip/hip_runtime.h>
#include <hip/hip_bf16.h>
#include <math.h>

#define Tn   2048
#define Cn   1536
#define Vn   32000
#define NHn  12
#define NKVn 4
#define Dn   128
#define HIDn 2048
#define En   8
#define Kn   2
#define Ln   2
#define NREPn 3
#define EPSn 1e-6f

using bf16 = __hip_bfloat16;
using bf16x8 = __attribute__((ext_vector_type(8))) short;
using f32x4v = __attribute__((ext_vector_type(4))) float;

// Exact 3-way bf16 split: v = hi + mid + lo + O(2^-33 * v)
__device__ __forceinline__ void split3(float v, short& h, short& m, short& lo) {
  bf16 b0 = __float2bfloat16(v);
  float r1 = v - __bfloat162float(b0);
  bf16 b1 = __float2bfloat16(r1);
  float r2 = r1 - __bfloat162float(b1);
  bf16 b2 = __float2bfloat16(r2);
  h = *reinterpret_cast<short*>(&b0);
  m = *reinterpret_cast<short*>(&b1);
  lo = *reinterpret_cast<short*>(&b2);
}

// ---------------- embed (validated) ----------------
__global__ void embed_k(const int* __restrict__ tok, const float* __restrict__ emb,
                        const float* __restrict__ pos, float* __restrict__ x) {
  int n = blockIdx.x;
  int t = threadIdx.x;
  int id = tok[n];
  const float* er = emb + (size_t)id * Cn;
  const float* pr = pos + (size_t)n * Cn;
  float* xr = x + (size_t)n * Cn;
  for (int c = t; c < Cn; c += 256) xr[c] = er[c] + pr[c];
}

// ---------------- RMSNorm fp32 (validated) ----------------
__global__ void rmsnorm_k(const float* __restrict__ x, const float* __restrict__ w,
                          float* __restrict__ out) {
  int n = blockIdx.x, t = threadIdx.x;
  const float* xr = x + (size_t)n * Cn;
  float v[6];
  float ss = 0.f;
#pragma unroll
  for (int i = 0; i < 6; i++) { v[i] = xr[t + i * 256]; ss += v[i] * v[i]; }
  for (int off = 32; off > 0; off >>= 1) ss += __shfl_down(ss, off, 64);
  __shared__ float red[4];
  __shared__ float rtot;
  int wave = t >> 6, lane = t & 63;
  if (lane == 0) red[wave] = ss;
  __syncthreads();
  if (t == 0) rtot = rsqrtf((red[0] + red[1] + red[2] + red[3]) / (float)Cn + EPSn);
  __syncthreads();
  float r = rtot;
  float* orow = out + (size_t)n * Cn;
#pragma unroll
  for (int i = 0; i < 6; i++) { int c = t + i * 256; orow[c] = v[i] * r * w[c]; }
}

// ---------------- fp32 -> bf16 (validated) ----------------
__global__ void f2b_k(const float* __restrict__ s, bf16* __restrict__ d, size_t n4) {
  size_t i = (size_t)blockIdx.x * 256 + threadIdx.x;
  size_t stride = (size_t)gridDim.x * 256;
  for (; i < n4; i += stride) {
    float4 v = ((const float4*)s)[i];
    d[i * 4 + 0] = __float2bfloat16(v.x);
    d[i * 4 + 1] = __float2bfloat16(v.y);
    d[i * 4 + 2] = __float2bfloat16(v.z);
    d[i * 4 + 3] = __float2bfloat16(v.w);
  }
}

// ---------------- MFMA GEMM pure bf16, Bt [N,K] (validated, logits tail only) ----------------
__global__ void __launch_bounds__(256) gemm_bt(const bf16* __restrict__ A, const bf16* __restrict__ Bt,
                                               const float* res, float* Co, int M, int N, int K) {
  int t = threadIdx.x;
  int l = t & 63, w = t >> 6;
  int bm = blockIdx.x * 128, bn = blockIdx.y * 128;
  int wr = (w >> 1) * 64, wc = (w & 1) * 64;
  const f32x4v zero = {0.f, 0.f, 0.f, 0.f};
  f32x4v acc[4][4];
#pragma unroll
  for (int i = 0; i < 4; i++)
#pragma unroll
    for (int j = 0; j < 4; j++) acc[i][j] = zero;
  int rl = l & 15, kg = (l >> 4) * 8;
  const bf16* arow[4];
  const bf16* brow[4];
#pragma unroll
  for (int i = 0; i < 4; i++) arow[i] = A + (size_t)(bm + wr + i * 16 + rl) * K + kg;
#pragma unroll
  for (int j = 0; j < 4; j++) brow[j] = Bt + (size_t)(bn + wc + j * 16 + rl) * K + kg;
  for (int k0 = 0; k0 < K; k0 += 32) {
    bf16x8 a[4], b[4];
#pragma unroll
    for (int i = 0; i < 4; i++) a[i] = *(const bf16x8*)(arow[i] + k0);
#pragma unroll
    for (int j = 0; j < 4; j++) b[j] = *(const bf16x8*)(brow[j] + k0);
#pragma unroll
    for (int i = 0; i < 4; i++)
#pragma unroll
      for (int j = 0; j < 4; j++)
        acc[i][j] = __builtin_amdgcn_mfma_f32_16x16x32_bf16(a[i], b[j], acc[i][j], 0, 0, 0);
  }
#pragma unroll
  for (int i = 0; i < 4; i++) {
    int rbase = bm + wr + i * 16 + (l >> 4) * 4;
#pragma unroll
    for (int j = 0; j < 4; j++) {
      int col = bn + wc + j * 16 + (l & 15);
#pragma unroll
      for (int r = 0; r < 4; r++) {
        size_t idx = (size_t)(rbase + r) * N + col;
        float v = acc[i][j][r];
        if (res) v += res[idx];
        Co[idx] = v;
      }
    }
  }
}

// ---------------- split-fp32 MFMA GEMM: C = A f32 [M,K] @ B f32 [K,N] (+res), bf16x3 x 6 products ----------------
__global__ void __launch_bounds__(256) gemm_x3(const float* __restrict__ A, const float* __restrict__ B,
                                               const float* res, float* __restrict__ Co,
                                               int M, int N, int K) {
  int t = threadIdx.x;
  int l = t & 63, w = t >> 6;
  int bm = blockIdx.x * 128, bn = blockIdx.y * 128;
  int wr = (w >> 1) * 64, wc = (w & 1) * 64;
  const f32x4v zero = {0.f, 0.f, 0.f, 0.f};
  f32x4v acc[4][4];
#pragma unroll
  for (int i = 0; i < 4; i++)
#pragma unroll
    for (int j = 0; j < 4; j++) acc[i][j] = zero;
  int rl = l & 15, kg = (l >> 4) * 8;
  const float* arow[4];
  int coln[4];
#pragma unroll
  for (int i = 0; i < 4; i++) arow[i] = A + (size_t)(bm + wr + i * 16 + rl) * K + kg;
#pragma unroll
  for (int j = 0; j < 4; j++) coln[j] = bn + wc + j * 16 + rl;
  for (int k0 = 0; k0 < K; k0 += 32) {
    bf16x8 aH[4], aM[4], aL[4], bH[4], bM[4], bL[4];
#pragma unroll
    for (int i = 0; i < 4; i++) {
      float4 u = *(const float4*)(arow[i] + k0);
      float4 v = *(const float4*)(arow[i] + k0 + 4);
      float av[8] = {u.x, u.y, u.z, u.w, v.x, v.y, v.z, v.w};
#pragma unroll
      for (int jj = 0; jj < 8; jj++) {
        short sh, sm, sl;
        split3(av[jj], sh, sm, sl);
        aH[i][jj] = sh; aM[i][jj] = sm; aL[i][jj] = sl;
      }
    }
    const float* bb = B + (size_t)(k0 + kg) * N;
#pragma unroll
    for (int j = 0; j < 4; j++)
#pragma unroll
      for (int jj = 0; jj < 8; jj++) {
        short sh, sm, sl;
        split3(bb[(size_t)jj * N + coln[j]], sh, sm, sl);
        bH[j][jj] = sh; bM[j][jj] = sm; bL[j][jj] = sl;
      }
#pragma unroll
    for (int i = 0; i < 4; i++)
#pragma unroll
      for (int j = 0; j < 4; j++) {
        acc[i][j] = __builtin_amdgcn_mfma_f32_16x16x32_bf16(aL[i], bH[j], acc[i][j], 0, 0, 0);
        acc[i][j] = __builtin_amdgcn_mfma_f32_16x16x32_bf16(aH[i], bL[j], acc[i][j], 0, 0, 0);
        acc[i][j] = __builtin_amdgcn_mfma_f32_16x16x32_bf16(aM[i], bM[j], acc[i][j], 0, 0, 0);
        acc[i][j] = __builtin_amdgcn_mfma_f32_16x16x32_bf16(aM[i], bH[j], acc[i][j], 0, 0, 0);
        acc[i][j] = __builtin_amdgcn_mfma_f32_16x16x32_bf16(aH[i], bM[j], acc[i][j], 0, 0, 0);
        acc[i][j] = __builtin_amdgcn_mfma_f32_16x16x32_bf16(aH[i], bH[j], acc[i][j], 0, 0, 0);
      }
  }
#pragma unroll
  for (int i = 0; i < 4; i++) {
    int rbase = bm + wr + i * 16 + (l >> 4) * 4;
#pragma unroll
    for (int j = 0; j < 4; j++) {
      int col = bn + wc + j * 16 + (l & 15);
#pragma unroll
      for (int r = 0; r < 4; r++) {
        size_t idx = (size_t)(rbase + r) * N + col;
        float v = acc[i][j][r];
        if (res) v += res[idx];
        Co[idx] = v;
      }
    }
  }
}

// ---------------- split-fp32 MoE expert GEMM (gathered A rows via perm) ----------------
// mode 0: out = silu(acc)          (up-proj pass 1, B = ew1)
// mode 1: out *= acc               (up-proj pass 2, B = ew3)
// mode 2: out = acc (pairout)      (down-proj, B = ew2, A rows = full pair idx)
__global__ void __launch_bounds__(256) mexp_x3(const float* __restrict__ Abase, const float* __restrict__ Ball,
                                               const int* __restrict__ perm, const int* __restrict__ cnt,
                                               float* __restrict__ Out, int K, int N, int mode) {
  int e = blockIdx.z;
  int nrows = cnt[e];
  int bm = blockIdx.x * 128;
  if (bm >= nrows) return;
  int bn = blockIdx.y * 128;
  const float* B = Ball + (size_t)e * K * N;
  __shared__ int prow[128];
  int t = threadIdx.x, l = t & 63, w = t >> 6;
  if (t < 128) {
    int i = bm + t;
    prow[t] = (i < nrows) ? perm[e * Tn + i] : -1;
  }
  __syncthreads();
  int wr = (w >> 1) * 64, wc = (w & 1) * 64;
  const f32x4v zero = {0.f, 0.f, 0.f, 0.f};
  f32x4v acc[4][4];
#pragma unroll
  for (int i = 0; i < 4; i++)
#pragma unroll
    for (int j = 0; j < 4; j++) acc[i][j] = zero;
  int rl = l & 15, kg = (l >> 4) * 8;
  const float* arow[4];
  int coln[4];
#pragma unroll
  for (int i = 0; i < 4; i++) {
    int p = prow[wr + i * 16 + rl];
    int ar = (p >= 0) ? (mode == 2 ? p : (p >> 1)) : 0;
    arow[i] = Abase + (size_t)ar * K + kg;
  }
#pragma unroll
  for (int j = 0; j < 4; j++) coln[j] = bn + wc + j * 16 + rl;
  for (int k0 = 0; k0 < K; k0 += 32) {
    bf16x8 aH[4], aM[4], aL[4], bH[4], bM[4], bL[4];
#pragma unroll
    for (int i = 0; i < 4; i++) {
      float4 u = *(const float4*)(arow[i] + k0);
      float4 v = *(const float4*)(arow[i] + k0 + 4);
      float av[8] = {u.x, u.y, u.z, u.w, v.x, v.y, v.z, v.w};
#pragma unroll
      for (int jj = 0; jj < 8; jj++) {
        short sh, sm, sl;
        split3(av[jj], sh, sm, sl);
        aH[i][jj] = sh; aM[i][jj] = sm; aL[i][jj] = sl;
      }
    }
    const float* bb = B + (size_t)(k0 + kg) * N;
#pragma unroll
    for (int j = 0; j < 4; j++)
#pragma unroll
      for (int jj = 0; jj < 8; jj++) {
        short sh, sm, sl;
        split3(bb[(size_t)jj * N + coln[j]], sh, sm, sl);
        bH[j][jj] = sh; bM[j][jj] = sm; bL[j][jj] = sl;
      }
#pragma unroll
    for (int i = 0; i < 4; i++)
#pragma unroll
      for (int j = 0; j < 4; j++) {
        acc[i][j] = __builtin_amdgcn_mfma_f32_16x16x32_bf16(aL[i], bH[j], acc[i][j], 0, 0, 0);
        acc[i][j] = __builtin_amdgcn_mfma_f32_16x16x32_bf16(aH[i], bL[j], acc[i][j], 0, 0, 0);
        acc[i][j] = __builtin_amdgcn_mfma_f32_16x16x32_bf16(aM[i], bM[j], acc[i][j], 0, 0, 0);
        acc[i][j] = __builtin_amdgcn_mfma_f32_16x16x32_bf16(aM[i], bH[j], acc[i][j], 0, 0, 0);
        acc[i][j] = __builtin_amdgcn_mfma_f32_16x16x32_bf16(aH[i], bM[j], acc[i][j], 0, 0, 0);
        acc[i][j] = __builtin_amdgcn_mfma_f32_16x16x32_bf16(aH[i], bH[j], acc[i][j], 0, 0, 0);
      }
  }
#pragma unroll
  for (int i = 0; i < 4; i++) {
#pragma unroll
    for (int r = 0; r < 4; r++) {
      int lrow = wr + i * 16 + (l >> 4) * 4 + r;
      int p = prow[lrow];
      if (p < 0) continue;
#pragma unroll
      for (int j = 0; j < 4; j++) {
        int col = bn + wc + j * 16 + (l & 15);
        size_t idx = (size_t)p * N + col;
        float v = acc[i][j][r];
        if (mode == 0) {
          Out[idx] = v / (1.f + expf(-v));        // silu(h1)
        } else if (mode == 1) {
          Out[idx] *= v;                           // * h3
        } else {
          Out[idx] = v;                            // pairout
        }
      }
    }
  }
}

// ---------------- causal GQA flash attention fp32 (validated) ----------------
__global__ void attn_f32_k(const float* __restrict__ q, const float* __restrict__ k,
                           const float* __restrict__ v, float* __restrict__ y) {
  int qt = blockIdx.x, head = blockIdx.y;
  int kvh = head / NREPn;
  int q0 = qt * 32;
  int t = threadIdx.x;
  __shared__ float qs[32][Dn + 1];
  __shared__ float ks[32][Dn + 1];
  __shared__ float vs[32][Dn + 1];
  __shared__ float sc[32][33];
  __shared__ float rowm[32], rowl[32], rowa[32];
  const float scale = 0.08838834764831845f;
  for (int e = t; e < 32 * Dn; e += 256) {
    int r = e >> 7, d = e & 127;
    qs[r][d] = q[(size_t)(q0 + r) * (NHn * Dn) + head * Dn + d] * scale;
  }
  if (t < 32) { rowm[t] = -1e30f; rowl[t] = 0.f; }
  float o[16];
#pragma unroll
  for (int j = 0; j < 16; j++) o[j] = 0.f;
  int r = t >> 3;
  int kb = (t & 7) * 4;
  int d0 = (t & 7) * 16;
  __syncthreads();
  for (int kt = 0; kt <= qt; kt++) {
    int kv0 = kt * 32;
    for (int e = t; e < 32 * Dn; e += 256) {
      int rr = e >> 7, d = e & 127;
      size_t off = (size_t)(kv0 + rr) * (NKVn * Dn) + kvh * Dn + d;
      ks[rr][d] = k[off];
      vs[rr][d] = v[off];
    }
    __syncthreads();
#pragma unroll
    for (int j = 0; j < 4; j++) {
      int kk = kb + j;
      float s = 0.f;
      for (int d = 0; d < Dn; d++) s += qs[r][d] * ks[kk][d];
      if (kt == qt && kk > r) s = -1e30f;
      sc[r][kk] = s;
    }
    __syncthreads();
    if (t < 32) {
      int rr = t;
      float mo = rowm[rr];
      float mx = mo;
      for (int kk = 0; kk < 32; kk++) mx = fmaxf(mx, sc[rr][kk]);
      float a = expf(mo - mx);
      float sum = 0.f;
      for (int kk = 0; kk < 32; kk++) {
        float p = expf(sc[rr][kk] - mx);
        sc[rr][kk] = p;
        sum += p;
      }
      rowl[rr] = rowl[rr] * a + sum;
      rowm[rr] = mx;
      rowa[rr] = a;
    }
    __syncthreads();
    float a = rowa[r];
#pragma unroll
    for (int j = 0; j < 16; j++) o[j] *= a;
    for (int kk = 0; kk < 32; kk++) {
      float p = sc[r][kk];
#pragma unroll
      for (int j = 0; j < 16; j++) o[j] += p * vs[kk][d0 + j];
    }
    __syncthreads();
  }
  float inv = 1.f / rowl[r];
#pragma unroll
  for (int j = 0; j < 16; j++)
    y[(size_t)(q0 + r) * (NHn * Dn) + head * Dn + d0 + j] = o[j] * inv;
}

// ---------------- gate logits (validated) ----------------
__global__ void gate_k(const float* __restrict__ xf, const float* __restrict__ g,
                       float* __restrict__ gl) {
  int n = blockIdx.x, t = threadIdx.x;
  int e = t & 7, cs = t >> 3;
  const float* xr = xf + (size_t)n * Cn;
  float s = 0.f;
  for (int j = 0; j < Cn / 32; j++) {
    int c = cs + 32 * j;
    s += xr[c] * g[c * En + e];
  }
  __shared__ float red[256];
  red[t] = s;
  __syncthreads();
  if (t < 8) {
    float tot = 0.f;
    for (int j = 0; j < 32; j++) tot += red[t + 8 * j];
    gl[n * En + t] = tot;
  }
}

// ---------------- routing (validated, Tn stride) ----------------
__global__ void route_k(const float* __restrict__ gl, float* __restrict__ topw,
                        int* __restrict__ cnt, int* __restrict__ perm) {
  int n = blockIdx.x * blockDim.x + threadIdx.x;
  if (n >= Tn) return;
  float p[En];
  float mx = -1e30f;
#pragma unroll
  for (int e = 0; e < En; e++) { p[e] = gl[n * En + e]; mx = fmaxf(mx, p[e]); }
  float s = 0.f;
#pragma unroll
  for (int e = 0; e < En; e++) { p[e] = expf(p[e] - mx); s += p[e]; }
  float invs = 1.f / s;
#pragma unroll
  for (int e = 0; e < En; e++) p[e] *= invs;
  int i0 = 0;
#pragma unroll
  for (int e = 1; e < En; e++) if (p[e] > p[i0]) i0 = e;
  int i1 = (i0 == 0) ? 1 : 0;
#pragma unroll
  for (int e = 0; e < En; e++) if (e != i0 && p[e] > p[i1]) i1 = e;
  float w0 = p[i0], w1 = p[i1], sw = w0 + w1;
  topw[2 * n]     = w0 / sw;
  topw[2 * n + 1] = w1 / sw;
  int pos0 = atomicAdd(&cnt[i0], 1);
  perm[i0 * Tn + pos0] = 2 * n;
  int pos1 = atomicAdd(&cnt[i1], 1);
  perm[i1 * Tn + pos1] = 2 * n + 1;
}

// ---------------- combine (validated) ----------------
__global__ void combine_k(const float* __restrict__ pairout, const float* __restrict__ topw,
                          float* __restrict__ x) {
  int n = blockIdx.x, t = threadIdx.x;
  float w0 = topw[2 * n], w1 = topw[2 * n + 1];
  const float* p0 = pairout + (size_t)(2 * n) * Cn;
  const float* p1 = pairout + (size_t)(2 * n + 1) * Cn;
  float* xr = x + (size_t)n * Cn;
  for (int c = t; c < Cn; c += 256) xr[c] += w0 * p0[c] + w1 * p1[c];
}

// =================================================================================
extern "C" void kernel_launch(void* const* d_in, const int* in_sizes, int n_in,
                              void* d_out, int out_size, void* d_ws, size_t ws_size,
                              hipStream_t stream) {
  const int*   tokens = (const int*)d_in[0];
  const float* emb    = (const float*)d_in[1];
  const float* pos    = (const float*)d_in[2];
  const float* wq     = (const float*)d_in[3];
  const float* wk     = (const float*)d_in[4];
  const float* wv     = (const float*)d_in[5];
  const float* wo     = (const float*)d_in[6];
  const float* attn_nw= (const float*)d_in[7];
  const float* ffn_nw = (const float*)d_in[8];
  const float* gate   = (const float*)d_in[9];
  const float* ew1    = (const float*)d_in[10];
  const float* ew2    = (const float*)d_in[11];
  const float* ew3    = (const float*)d_in[12];
  const float* final_nw = (const float*)d_in[13];
  float* out = (float*)d_out;

  char* wsb = (char*)d_ws;
  const size_t NC = (size_t)Tn * Cn;
  size_t off = 0;
  auto alloc = [&](size_t bytes) -> size_t {
    off = (off + 255) & ~(size_t)255;
    size_t p = off;
    off += bytes;
    return p;
  };
  // Proven 129.8 MB layout (round 5/7 footprint).
  size_t o_x    = alloc(NC * 4);
  size_t o_h    = alloc(NC * 4);
  size_t o_hb   = alloc(NC * 2);
  size_t o_pool = off;
  size_t o_qb   = alloc(NC * 4);
  size_t o_kb   = alloc((size_t)Tn * NKVn * Dn * 4);
  size_t o_vb   = alloc((size_t)Tn * NKVn * Dn * 4);
  size_t o_yb   = alloc(NC * 4);
  size_t o_gl   = alloc((size_t)Tn * En * 4);
  size_t o_topw = alloc((size_t)Tn * Kn * 4);
  size_t o_hbuf = alloc((size_t)Tn * Kn * HIDn * 4);
  size_t o_pair = alloc((size_t)Tn * Kn * Cn * 4);
  size_t o_cnt  = alloc(64);
  size_t o_perm = alloc((size_t)En * Tn * 4);
  size_t embB_bytes = (size_t)Vn * Cn * 2;
  if (off - o_pool < embB_bytes) off = o_pool + embB_bytes;  // embB aliases dead pool at tail

  float* x       = (float*)(wsb + o_x);
  float* h       = (float*)(wsb + o_h);
  bf16*  hb      = (bf16*)(wsb + o_hb);
  float* qb      = (float*)(wsb + o_qb);
  float* kb      = (float*)(wsb + o_kb);
  float* vb      = (float*)(wsb + o_vb);
  float* yb      = (float*)(wsb + o_yb);
  float* gl      = (float*)(wsb + o_gl);
  float* topw    = (float*)(wsb + o_topw);
  float* hbuf    = (float*)(wsb + o_hbuf);
  float* pairout = (float*)(wsb + o_pair);
  int*   cnt     = (int*)(wsb + o_cnt);
  int*   perm    = (int*)(wsb + o_perm);
  bf16*  embB    = (bf16*)(wsb + o_pool);

  embed_k<<<Tn, 256, 0, stream>>>(tokens, emb, pos, x);
  for (int l = 0; l < Ln; l++) {
    const float* wq_l = wq + (size_t)l * Cn * (NHn * Dn);
    const float* wk_l = wk + (size_t)l * Cn * (NKVn * Dn);
    const float* wv_l = wv + (size_t)l * Cn * (NKVn * Dn);
    const float* wo_l = wo + (size_t)l * Cn * Cn;
    const float* g_l  = gate + (size_t)l * Cn * En;
    const float* e1_l = ew1 + (size_t)l * En * Cn * HIDn;
    const float* e2_l = ew2 + (size_t)l * En * HIDn * Cn;
    const float* e3_l = ew3 + (size_t)l * En * Cn * HIDn;

    // --- attention: split-fp32 MFMA projections + validated fp32 core ---
    rmsnorm_k<<<Tn, 256, 0, stream>>>(x, attn_nw + (size_t)l * Cn, h);
    gemm_x3<<<dim3(Tn / 128, (NHn * Dn) / 128), 256, 0, stream>>>(h, wq_l, nullptr, qb, Tn, NHn * Dn, Cn);
    gemm_x3<<<dim3(Tn / 128, (NKVn * Dn) / 128), 256, 0, stream>>>(h, wk_l, nullptr, kb, Tn, NKVn * Dn, Cn);
    gemm_x3<<<dim3(Tn / 128, (NKVn * Dn) / 128), 256, 0, stream>>>(h, wv_l, nullptr, vb, Tn, NKVn * Dn, Cn);
    attn_f32_k<<<dim3(Tn / 32, NHn), 256, 0, stream>>>(qb, kb, vb, yb);
    gemm_x3<<<dim3(Tn / 128, Cn / 128), 256, 0, stream>>>(yb, wo_l, x, x, Tn, Cn, Cn);

    // --- MoE: routing fp32, expert GEMMs split-fp32 MFMA ---
    rmsnorm_k<<<Tn, 256, 0, stream>>>(x, ffn_nw + (size_t)l * Cn, h);
    gate_k<<<Tn, 256, 0, stream>>>(h, g_l, gl);
    hipMemsetAsync(cnt, 0, 64, stream);
    route_k<<<Tn / 256, 256, 0, stream>>>(gl, topw, cnt, perm);
    mexp_x3<<<dim3(Tn / 128, HIDn / 128, En), 256, 0, stream>>>(h, e1_l, perm, cnt, hbuf, Cn, HIDn, 0);
    mexp_x3<<<dim3(Tn / 128, HIDn / 128, En), 256, 0, stream>>>(h, e3_l, perm, cnt, hbuf, Cn, HIDn, 1);
    mexp_x3<<<dim3(Tn / 128, Cn / 128, En), 256, 0, stream>>>(hbuf, e2_l, perm, cnt, pairout, HIDn, Cn, 2);
    combine_k<<<Tn, 256, 0, stream>>>(pairout, topw, x);
  }
  // --- validated bf16 logits tail (downstream of all routing) ---
  rmsnorm_k<<<Tn, 256, 0, stream>>>(x, final_nw, h);
  f2b_k<<<2048, 256, 0, stream>>>(h, hb, NC / 4);
  f2b_k<<<2048, 256, 0, stream>>>(emb, embB, (size_t)Vn * Cn / 4);
  gemm_bt<<<dim3(Tn / 128, Vn / 128), 256, 0, stream>>>(hb, embB, nullptr, out, Tn, Vn, Cn);
}

// Round 9
// 10123.902 us; speedup vs baseline: 2.4269x; 1.5876x over previous
//
#include <hip/hip_runtime.h>
#include <hip/hip_bf16.h>
#include <math.h>

#define Tn   2048
#define Cn   1536
#define Vn   32000
#define NHn  12
#define NKVn 4
#define Dn   128
#define HIDn 2048
#define En   8
#define Kn   2
#define Ln   2
#define NREPn 3
#define EPSn 1e-6f

using bf16 = __hip_bfloat16;
using bf16x8 = __attribute__((ext_vector_type(8))) short;
using f32x4v = __attribute__((ext_vector_type(4))) float;

// Exact 3-way bf16 split: v = hi + mid + lo + O(2^-27 * v)
__device__ __forceinline__ void split3(float v, short& h, short& m, short& lo) {
  bf16 b0 = __float2bfloat16(v);
  float r1 = v - __bfloat162float(b0);
  bf16 b1 = __float2bfloat16(r1);
  float r2 = r1 - __bfloat162float(b1);
  bf16 b2 = __float2bfloat16(r2);
  h = *reinterpret_cast<short*>(&b0);
  m = *reinterpret_cast<short*>(&b1);
  lo = *reinterpret_cast<short*>(&b2);
}

// ---------------- embed (validated) ----------------
__global__ void embed_k(const int* __restrict__ tok, const float* __restrict__ emb,
                        const float* __restrict__ pos, float* __restrict__ x) {
  int n = blockIdx.x;
  int t = threadIdx.x;
  int id = tok[n];
  const float* er = emb + (size_t)id * Cn;
  const float* pr = pos + (size_t)n * Cn;
  float* xr = x + (size_t)n * Cn;
  for (int c = t; c < Cn; c += 256) xr[c] = er[c] + pr[c];
}

// ---------------- RMSNorm fp32 (validated) ----------------
__global__ void rmsnorm_k(const float* __restrict__ x, const float* __restrict__ w,
                          float* __restrict__ out) {
  int n = blockIdx.x, t = threadIdx.x;
  const float* xr = x + (size_t)n * Cn;
  float v[6];
  float ss = 0.f;
#pragma unroll
  for (int i = 0; i < 6; i++) { v[i] = xr[t + i * 256]; ss += v[i] * v[i]; }
  for (int off = 32; off > 0; off >>= 1) ss += __shfl_down(ss, off, 64);
  __shared__ float red[4];
  __shared__ float rtot;
  int wave = t >> 6, lane = t & 63;
  if (lane == 0) red[wave] = ss;
  __syncthreads();
  if (t == 0) rtot = rsqrtf((red[0] + red[1] + red[2] + red[3]) / (float)Cn + EPSn);
  __syncthreads();
  float r = rtot;
  float* orow = out + (size_t)n * Cn;
#pragma unroll
  for (int i = 0; i < 6; i++) { int c = t + i * 256; orow[c] = v[i] * r * w[c]; }
}

// ---------------- fp32 -> bf16 (validated) ----------------
__global__ void f2b_k(const float* __restrict__ s, bf16* __restrict__ d, size_t n4) {
  size_t i = (size_t)blockIdx.x * 256 + threadIdx.x;
  size_t stride = (size_t)gridDim.x * 256;
  for (; i < n4; i += stride) {
    float4 v = ((const float4*)s)[i];
    d[i * 4 + 0] = __float2bfloat16(v.x);
    d[i * 4 + 1] = __float2bfloat16(v.y);
    d[i * 4 + 2] = __float2bfloat16(v.z);
    d[i * 4 + 3] = __float2bfloat16(v.w);
  }
}

// ---------------- MFMA GEMM pure bf16, Bt [N,K] (validated, logits tail only) ----------------
__global__ void __launch_bounds__(256) gemm_bt(const bf16* __restrict__ A, const bf16* __restrict__ Bt,
                                               const float* res, float* Co, int M, int N, int K) {
  int t = threadIdx.x;
  int l = t & 63, w = t >> 6;
  int bm = blockIdx.x * 128, bn = blockIdx.y * 128;
  int wr = (w >> 1) * 64, wc = (w & 1) * 64;
  const f32x4v zero = {0.f, 0.f, 0.f, 0.f};
  f32x4v acc[4][4];
#pragma unroll
  for (int i = 0; i < 4; i++)
#pragma unroll
    for (int j = 0; j < 4; j++) acc[i][j] = zero;
  int rl = l & 15, kg = (l >> 4) * 8;
  const bf16* arow[4];
  const bf16* brow[4];
#pragma unroll
  for (int i = 0; i < 4; i++) arow[i] = A + (size_t)(bm + wr + i * 16 + rl) * K + kg;
#pragma unroll
  for (int j = 0; j < 4; j++) brow[j] = Bt + (size_t)(bn + wc + j * 16 + rl) * K + kg;
  for (int k0 = 0; k0 < K; k0 += 32) {
    bf16x8 a[4], b[4];
#pragma unroll
    for (int i = 0; i < 4; i++) a[i] = *(const bf16x8*)(arow[i] + k0);
#pragma unroll
    for (int j = 0; j < 4; j++) b[j] = *(const bf16x8*)(brow[j] + k0);
#pragma unroll
    for (int i = 0; i < 4; i++)
#pragma unroll
      for (int j = 0; j < 4; j++)
        acc[i][j] = __builtin_amdgcn_mfma_f32_16x16x32_bf16(a[i], b[j], acc[i][j], 0, 0, 0);
  }
#pragma unroll
  for (int i = 0; i < 4; i++) {
    int rbase = bm + wr + i * 16 + (l >> 4) * 4;
#pragma unroll
    for (int j = 0; j < 4; j++) {
      int col = bn + wc + j * 16 + (l & 15);
#pragma unroll
      for (int r = 0; r < 4; r++) {
        size_t idx = (size_t)(rbase + r) * N + col;
        float v = acc[i][j][r];
        if (res) v += res[idx];
        Co[idx] = v;
      }
    }
  }
}

// ---------------- split-fp32 MFMA GEMM: C = A f32 [M,K] @ B f32 [K,N] (+res) ----------------
__global__ void __launch_bounds__(256) gemm_x3(const float* __restrict__ A, const float* __restrict__ B,
                                               const float* res, float* __restrict__ Co,
                                               int M, int N, int K) {
  int t = threadIdx.x;
  int l = t & 63, w = t >> 6;
  int bm = blockIdx.x * 128, bn = blockIdx.y * 128;
  int wr = (w >> 1) * 64, wc = (w & 1) * 64;
  const f32x4v zero = {0.f, 0.f, 0.f, 0.f};
  f32x4v acc[4][4];
#pragma unroll
  for (int i = 0; i < 4; i++)
#pragma unroll
    for (int j = 0; j < 4; j++) acc[i][j] = zero;
  int rl = l & 15, kg = (l >> 4) * 8;
  const float* arow[4];
  int coln[4];
#pragma unroll
  for (int i = 0; i < 4; i++) arow[i] = A + (size_t)(bm + wr + i * 16 + rl) * K + kg;
#pragma unroll
  for (int j = 0; j < 4; j++) coln[j] = bn + wc + j * 16 + rl;
  for (int k0 = 0; k0 < K; k0 += 32) {
    bf16x8 aH[4], aM[4], aL[4], bH[4], bM[4], bL[4];
#pragma unroll
    for (int i = 0; i < 4; i++) {
      float4 u = *(const float4*)(arow[i] + k0);
      float4 v = *(const float4*)(arow[i] + k0 + 4);
      float av[8] = {u.x, u.y, u.z, u.w, v.x, v.y, v.z, v.w};
#pragma unroll
      for (int jj = 0; jj < 8; jj++) {
        short sh, sm, sl;
        split3(av[jj], sh, sm, sl);
        aH[i][jj] = sh; aM[i][jj] = sm; aL[i][jj] = sl;
      }
    }
    const float* bb = B + (size_t)(k0 + kg) * N;
#pragma unroll
    for (int j = 0; j < 4; j++)
#pragma unroll
      for (int jj = 0; jj < 8; jj++) {
        short sh, sm, sl;
        split3(bb[(size_t)jj * N + coln[j]], sh, sm, sl);
        bH[j][jj] = sh; bM[j][jj] = sm; bL[j][jj] = sl;
      }
#pragma unroll
    for (int i = 0; i < 4; i++)
#pragma unroll
      for (int j = 0; j < 4; j++) {
        acc[i][j] = __builtin_amdgcn_mfma_f32_16x16x32_bf16(aL[i], bH[j], acc[i][j], 0, 0, 0);
        acc[i][j] = __builtin_amdgcn_mfma_f32_16x16x32_bf16(aH[i], bL[j], acc[i][j], 0, 0, 0);
        acc[i][j] = __builtin_amdgcn_mfma_f32_16x16x32_bf16(aM[i], bM[j], acc[i][j], 0, 0, 0);
        acc[i][j] = __builtin_amdgcn_mfma_f32_16x16x32_bf16(aM[i], bH[j], acc[i][j], 0, 0, 0);
        acc[i][j] = __builtin_amdgcn_mfma_f32_16x16x32_bf16(aH[i], bM[j], acc[i][j], 0, 0, 0);
        acc[i][j] = __builtin_amdgcn_mfma_f32_16x16x32_bf16(aH[i], bH[j], acc[i][j], 0, 0, 0);
      }
  }
#pragma unroll
  for (int i = 0; i < 4; i++) {
    int rbase = bm + wr + i * 16 + (l >> 4) * 4;
#pragma unroll
    for (int j = 0; j < 4; j++) {
      int col = bn + wc + j * 16 + (l & 15);
#pragma unroll
      for (int r = 0; r < 4; r++) {
        size_t idx = (size_t)(rbase + r) * N + col;
        float v = acc[i][j][r];
        if (res) v += res[idx];
        Co[idx] = v;
      }
    }
  }
}

// ---------------- split-fp32 MoE expert GEMM (gathered A rows via perm) ----------------
__global__ void __launch_bounds__(256) mexp_x3(const float* __restrict__ Abase, const float* __restrict__ Ball,
                                               const int* __restrict__ perm, const int* __restrict__ cnt,
                                               float* __restrict__ Out, int K, int N, int mode) {
  int e = blockIdx.z;
  int nrows = cnt[e];
  int bm = blockIdx.x * 128;
  if (bm >= nrows) return;
  int bn = blockIdx.y * 128;
  const float* B = Ball + (size_t)e * K * N;
  __shared__ int prow[128];
  int t = threadIdx.x, l = t & 63, w = t >> 6;
  if (t < 128) {
    int i = bm + t;
    prow[t] = (i < nrows) ? perm[e * Tn + i] : -1;
  }
  __syncthreads();
  int wr = (w >> 1) * 64, wc = (w & 1) * 64;
  const f32x4v zero = {0.f, 0.f, 0.f, 0.f};
  f32x4v acc[4][4];
#pragma unroll
  for (int i = 0; i < 4; i++)
#pragma unroll
    for (int j = 0; j < 4; j++) acc[i][j] = zero;
  int rl = l & 15, kg = (l >> 4) * 8;
  const float* arow[4];
  int coln[4];
#pragma unroll
  for (int i = 0; i < 4; i++) {
    int p = prow[wr + i * 16 + rl];
    int ar = (p >= 0) ? (mode == 2 ? p : (p >> 1)) : 0;
    arow[i] = Abase + (size_t)ar * K + kg;
  }
#pragma unroll
  for (int j = 0; j < 4; j++) coln[j] = bn + wc + j * 16 + rl;
  for (int k0 = 0; k0 < K; k0 += 32) {
    bf16x8 aH[4], aM[4], aL[4], bH[4], bM[4], bL[4];
#pragma unroll
    for (int i = 0; i < 4; i++) {
      float4 u = *(const float4*)(arow[i] + k0);
      float4 v = *(const float4*)(arow[i] + k0 + 4);
      float av[8] = {u.x, u.y, u.z, u.w, v.x, v.y, v.z, v.w};
#pragma unroll
      for (int jj = 0; jj < 8; jj++) {
        short sh, sm, sl;
        split3(av[jj], sh, sm, sl);
        aH[i][jj] = sh; aM[i][jj] = sm; aL[i][jj] = sl;
      }
    }
    const float* bb = B + (size_t)(k0 + kg) * N;
#pragma unroll
    for (int j = 0; j < 4; j++)
#pragma unroll
      for (int jj = 0; jj < 8; jj++) {
        short sh, sm, sl;
        split3(bb[(size_t)jj * N + coln[j]], sh, sm, sl);
        bH[j][jj] = sh; bM[j][jj] = sm; bL[j][jj] = sl;
      }
#pragma unroll
    for (int i = 0; i < 4; i++)
#pragma unroll
      for (int j = 0; j < 4; j++) {
        acc[i][j] = __builtin_amdgcn_mfma_f32_16x16x32_bf16(aL[i], bH[j], acc[i][j], 0, 0, 0);
        acc[i][j] = __builtin_amdgcn_mfma_f32_16x16x32_bf16(aH[i], bL[j], acc[i][j], 0, 0, 0);
        acc[i][j] = __builtin_amdgcn_mfma_f32_16x16x32_bf16(aM[i], bM[j], acc[i][j], 0, 0, 0);
        acc[i][j] = __builtin_amdgcn_mfma_f32_16x16x32_bf16(aM[i], bH[j], acc[i][j], 0, 0, 0);
        acc[i][j] = __builtin_amdgcn_mfma_f32_16x16x32_bf16(aH[i], bM[j], acc[i][j], 0, 0, 0);
        acc[i][j] = __builtin_amdgcn_mfma_f32_16x16x32_bf16(aH[i], bH[j], acc[i][j], 0, 0, 0);
      }
  }
#pragma unroll
  for (int i = 0; i < 4; i++) {
#pragma unroll
    for (int r = 0; r < 4; r++) {
      int lrow = wr + i * 16 + (l >> 4) * 4 + r;
      int p = prow[lrow];
      if (p < 0) continue;
#pragma unroll
      for (int j = 0; j < 4; j++) {
        int col = bn + wc + j * 16 + (l & 15);
        size_t idx = (size_t)p * N + col;
        float v = acc[i][j][r];
        if (mode == 0) {
          Out[idx] = v / (1.f + expf(-v));
        } else if (mode == 1) {
          Out[idx] *= v;
        } else {
          Out[idx] = v;
        }
      }
    }
  }
}

// ---------------- NEW: register-resident fp32 flash attention ----------------
// Thread (r=t>>3, g=t&7): Q-row slice in regs, shfl-reduced scores, per-thread
// online softmax (replicated x8 per row), 2 barriers/tile. All 256 threads active.
__global__ void __launch_bounds__(256) attn_fast_k(const float* __restrict__ q,
                                                   const float* __restrict__ k,
                                                   const float* __restrict__ v,
                                                   float* __restrict__ y) {
  int qt = blockIdx.x, head = blockIdx.y;
  int kvh = head / NREPn;
  int q0 = qt * 32;
  int t = threadIdx.x;
  int r = t >> 3, g = t & 7, d0 = g * 16;
  __shared__ __align__(16) float ks[32][Dn + 4];
  __shared__ __align__(16) float vs[32][Dn + 4];
  const float scale = 0.08838834764831845f;  // 1/sqrt(128)
  float qr[16];
  {
    const float* qrow = q + (size_t)(q0 + r) * (NHn * Dn) + head * Dn + d0;
#pragma unroll
    for (int j = 0; j < 16; j += 4) {
      float4 u = *(const float4*)(qrow + j);
      qr[j] = u.x * scale; qr[j + 1] = u.y * scale;
      qr[j + 2] = u.z * scale; qr[j + 3] = u.w * scale;
    }
  }
  float o[16];
#pragma unroll
  for (int j = 0; j < 16; j++) o[j] = 0.f;
  float rowm = -1e30f, rowl = 0.f;

  for (int kt = 0; kt <= qt; kt++) {
    int kv0 = kt * 32;
    // stage K/V tile (coalesced float4)
    for (int e = t; e < 32 * 32; e += 256) {
      int rr = e >> 5, c4 = (e & 31) * 4;
      size_t off = (size_t)(kv0 + rr) * (NKVn * Dn) + kvh * Dn + c4;
      *(float4*)&ks[rr][c4] = *(const float4*)(k + off);
      *(float4*)&vs[rr][c4] = *(const float4*)(v + off);
    }
    __syncthreads();

    // scores: partial dot over 16 d-elems, butterfly-reduce across 8-lane row group
    float s[32];
#pragma unroll
    for (int kk = 0; kk < 32; kk++) {
      const float* krow = &ks[kk][d0];
      float p = 0.f;
#pragma unroll
      for (int j = 0; j < 16; j += 4) {
        float4 u = *(const float4*)(krow + j);
        p += qr[j] * u.x + qr[j + 1] * u.y + qr[j + 2] * u.z + qr[j + 3] * u.w;
      }
      p += __shfl_xor(p, 1);
      p += __shfl_xor(p, 2);
      p += __shfl_xor(p, 4);
      s[kk] = p;
    }
    if (kt == qt) {
#pragma unroll
      for (int kk = 0; kk < 32; kk++)
        if (kk > r) s[kk] = -1e30f;
    }
    // online softmax (per-thread, identical across the 8-lane group)
    float mx = s[0];
#pragma unroll
    for (int kk = 1; kk < 32; kk++) mx = fmaxf(mx, s[kk]);
    float m_new = fmaxf(rowm, mx);
    float corr = expf(rowm - m_new);
    float sum = 0.f;
#pragma unroll
    for (int kk = 0; kk < 32; kk++) { s[kk] = expf(s[kk] - m_new); sum += s[kk]; }
    rowl = rowl * corr + sum;
    rowm = m_new;
#pragma unroll
    for (int j = 0; j < 16; j++) o[j] *= corr;
    // PV accumulate
#pragma unroll
    for (int kk = 0; kk < 32; kk++) {
      float p = s[kk];
      const float* vrow = &vs[kk][d0];
#pragma unroll
      for (int j = 0; j < 16; j += 4) {
        float4 u = *(const float4*)(vrow + j);
        o[j] += p * u.x; o[j + 1] += p * u.y; o[j + 2] += p * u.z; o[j + 3] += p * u.w;
      }
    }
    __syncthreads();
  }
  float inv = 1.f / rowl;
  float* yrow = y + (size_t)(q0 + r) * (NHn * Dn) + head * Dn + d0;
#pragma unroll
  for (int j = 0; j < 16; j += 4) {
    float4 u;
    u.x = o[j] * inv; u.y = o[j + 1] * inv; u.z = o[j + 2] * inv; u.w = o[j + 3] * inv;
    *(float4*)(yrow + j) = u;
  }
}

// ---------------- gate logits (validated) ----------------
__global__ void gate_k(const float* __restrict__ xf, const float* __restrict__ g,
                       float* __restrict__ gl) {
  int n = blockIdx.x, t = threadIdx.x;
  int e = t & 7, cs = t >> 3;
  const float* xr = xf + (size_t)n * Cn;
  float s = 0.f;
  for (int j = 0; j < Cn / 32; j++) {
    int c = cs + 32 * j;
    s += xr[c] * g[c * En + e];
  }
  __shared__ float red[256];
  red[t] = s;
  __syncthreads();
  if (t < 8) {
    float tot = 0.f;
    for (int j = 0; j < 32; j++) tot += red[t + 8 * j];
    gl[n * En + t] = tot;
  }
}

// ---------------- routing (validated, Tn stride) ----------------
__global__ void route_k(const float* __restrict__ gl, float* __restrict__ topw,
                        int* __restrict__ cnt, int* __restrict__ perm) {
  int n = blockIdx.x * blockDim.x + threadIdx.x;
  if (n >= Tn) return;
  float p[En];
  float mx = -1e30f;
#pragma unroll
  for (int e = 0; e < En; e++) { p[e] = gl[n * En + e]; mx = fmaxf(mx, p[e]); }
  float s = 0.f;
#pragma unroll
  for (int e = 0; e < En; e++) { p[e] = expf(p[e] - mx); s += p[e]; }
  float invs = 1.f / s;
#pragma unroll
  for (int e = 0; e < En; e++) p[e] *= invs;
  int i0 = 0;
#pragma unroll
  for (int e = 1; e < En; e++) if (p[e] > p[i0]) i0 = e;
  int i1 = (i0 == 0) ? 1 : 0;
#pragma unroll
  for (int e = 0; e < En; e++) if (e != i0 && p[e] > p[i1]) i1 = e;
  float w0 = p[i0], w1 = p[i1], sw = w0 + w1;
  topw[2 * n]     = w0 / sw;
  topw[2 * n + 1] = w1 / sw;
  int pos0 = atomicAdd(&cnt[i0], 1);
  perm[i0 * Tn + pos0] = 2 * n;
  int pos1 = atomicAdd(&cnt[i1], 1);
  perm[i1 * Tn + pos1] = 2 * n + 1;
}

// ---------------- combine (validated) ----------------
__global__ void combine_k(const float* __restrict__ pairout, const float* __restrict__ topw,
                          float* __restrict__ x) {
  int n = blockIdx.x, t = threadIdx.x;
  float w0 = topw[2 * n], w1 = topw[2 * n + 1];
  const float* p0 = pairout + (size_t)(2 * n) * Cn;
  const float* p1 = pairout + (size_t)(2 * n + 1) * Cn;
  float* xr = x + (size_t)n * Cn;
  for (int c = t; c < Cn; c += 256) xr[c] += w0 * p0[c] + w1 * p1[c];
}

// =================================================================================
extern "C" void kernel_launch(void* const* d_in, const int* in_sizes, int n_in,
                              void* d_out, int out_size, void* d_ws, size_t ws_size,
                              hipStream_t stream) {
  const int*   tokens = (const int*)d_in[0];
  const float* emb    = (const float*)d_in[1];
  const float* pos    = (const float*)d_in[2];
  const float* wq     = (const float*)d_in[3];
  const float* wk     = (const float*)d_in[4];
  const float* wv     = (const float*)d_in[5];
  const float* wo     = (const float*)d_in[6];
  const float* attn_nw= (const float*)d_in[7];
  const float* ffn_nw = (const float*)d_in[8];
  const float* gate   = (const float*)d_in[9];
  const float* ew1    = (const float*)d_in[10];
  const float* ew2    = (const float*)d_in[11];
  const float* ew3    = (const float*)d_in[12];
  const float* final_nw = (const float*)d_in[13];
  float* out = (float*)d_out;

  char* wsb = (char*)d_ws;
  const size_t NC = (size_t)Tn * Cn;
  size_t off = 0;
  auto alloc = [&](size_t bytes) -> size_t {
    off = (off + 255) & ~(size_t)255;
    size_t p = off;
    off += bytes;
    return p;
  };
  // Proven 129.8 MB layout (round 5/7/8 footprint).
  size_t o_x    = alloc(NC * 4);
  size_t o_h    = alloc(NC * 4);
  size_t o_hb   = alloc(NC * 2);
  size_t o_pool = off;
  size_t o_qb   = alloc(NC * 4);
  size_t o_kb   = alloc((size_t)Tn * NKVn * Dn * 4);
  size_t o_vb   = alloc((size_t)Tn * NKVn * Dn * 4);
  size_t o_yb   = alloc(NC * 4);
  size_t o_gl   = alloc((size_t)Tn * En * 4);
  size_t o_topw = alloc((size_t)Tn * Kn * 4);
  size_t o_hbuf = alloc((size_t)Tn * Kn * HIDn * 4);
  size_t o_pair = alloc((size_t)Tn * Kn * Cn * 4);
  size_t o_cnt  = alloc(64);
  size_t o_perm = alloc((size_t)En * Tn * 4);
  size_t embB_bytes = (size_t)Vn * Cn * 2;
  if (off - o_pool < embB_bytes) off = o_pool + embB_bytes;  // embB aliases dead pool at tail

  float* x       = (float*)(wsb + o_x);
  float* h       = (float*)(wsb + o_h);
  bf16*  hb      = (bf16*)(wsb + o_hb);
  float* qb      = (float*)(wsb + o_qb);
  float* kb      = (float*)(wsb + o_kb);
  float* vb      = (float*)(wsb + o_vb);
  float* yb      = (float*)(wsb + o_yb);
  float* gl      = (float*)(wsb + o_gl);
  float* topw    = (float*)(wsb + o_topw);
  float* hbuf    = (float*)(wsb + o_hbuf);
  float* pairout = (float*)(wsb + o_pair);
  int*   cnt     = (int*)(wsb + o_cnt);
  int*   perm    = (int*)(wsb + o_perm);
  bf16*  embB    = (bf16*)(wsb + o_pool);

  embed_k<<<Tn, 256, 0, stream>>>(tokens, emb, pos, x);
  for (int l = 0; l < Ln; l++) {
    const float* wq_l = wq + (size_t)l * Cn * (NHn * Dn);
    const float* wk_l = wk + (size_t)l * Cn * (NKVn * Dn);
    const float* wv_l = wv + (size_t)l * Cn * (NKVn * Dn);
    const float* wo_l = wo + (size_t)l * Cn * Cn;
    const float* g_l  = gate + (size_t)l * Cn * En;
    const float* e1_l = ew1 + (size_t)l * En * Cn * HIDn;
    const float* e2_l = ew2 + (size_t)l * En * HIDn * Cn;
    const float* e3_l = ew3 + (size_t)l * En * Cn * HIDn;

    // --- attention: split-fp32 MFMA projections + NEW register-flash fp32 core ---
    rmsnorm_k<<<Tn, 256, 0, stream>>>(x, attn_nw + (size_t)l * Cn, h);
    gemm_x3<<<dim3(Tn / 128, (NHn * Dn) / 128), 256, 0, stream>>>(h, wq_l, nullptr, qb, Tn, NHn * Dn, Cn);
    gemm_x3<<<dim3(Tn / 128, (NKVn * Dn) / 128), 256, 0, stream>>>(h, wk_l, nullptr, kb, Tn, NKVn * Dn, Cn);
    gemm_x3<<<dim3(Tn / 128, (NKVn * Dn) / 128), 256, 0, stream>>>(h, wv_l, nullptr, vb, Tn, NKVn * Dn, Cn);
    attn_fast_k<<<dim3(Tn / 32, NHn), 256, 0, stream>>>(qb, kb, vb, yb);
    gemm_x3<<<dim3(Tn / 128, Cn / 128), 256, 0, stream>>>(yb, wo_l, x, x, Tn, Cn, Cn);

    // --- MoE: routing fp32, expert GEMMs split-fp32 MFMA ---
    rmsnorm_k<<<Tn, 256, 0, stream>>>(x, ffn_nw + (size_t)l * Cn, h);
    gate_k<<<Tn, 256, 0, stream>>>(h, g_l, gl);
    hipMemsetAsync(cnt, 0, 64, stream);
    route_k<<<Tn / 256, 256, 0, stream>>>(gl, topw, cnt, perm);
    mexp_x3<<<dim3(Tn / 128, HIDn / 128, En), 256, 0, stream>>>(h, e1_l, perm, cnt, hbuf, Cn, HIDn, 0);
    mexp_x3<<<dim3(Tn / 128, HIDn / 128, En), 256, 0, stream>>>(h, e3_l, perm, cnt, hbuf, Cn, HIDn, 1);
    mexp_x3<<<dim3(Tn / 128, Cn / 128, En), 256, 0, stream>>>(hbuf, e2_l, perm, cnt, pairout, HIDn, Cn, 2);
    combine_k<<<Tn, 256, 0, stream>>>(pairout, topw, x);
  }
  // --- validated bf16 logits tail (downstream of all routing) ---
  rmsnorm_k<<<Tn, 256, 0, stream>>>(x, final_nw, h);
  f2b_k<<<2048, 256, 0, stream>>>(h, hb, NC / 4);
  f2b_k<<<2048, 256, 0, stream>>>(emb, embB, (size_t)Vn * Cn / 4);
  gemm_bt<<<dim3(Tn / 128, Vn / 128), 256, 0, stream>>>(hb, embB, nullptr, out, Tn, Vn, Cn);
}